// Round 1
// baseline (382.049 us; speedup 1.0000x reference)
//
#include <hip/hip_runtime.h>

typedef unsigned short u16;
typedef __attribute__((ext_vector_type(4))) float floatx4;
typedef __attribute__((ext_vector_type(8))) short shortx8;

// ---------- helpers ----------
__device__ __forceinline__ u16 f2b(float f) {
    // round-to-nearest-even fp32 -> bf16 (no NaN inputs in this problem)
    unsigned int u = __float_as_uint(f);
    unsigned int r = (u + 0x7fffu + ((u >> 16) & 1u)) >> 16;
    return (u16)r;
}
__device__ __forceinline__ float b2f(u16 u) {
    return __uint_as_float(((unsigned int)u) << 16);
}

// ---------- fp32 -> bf16 conversion (weights) ----------
__global__ __launch_bounds__(256) void cvt_kernel(const float* __restrict__ in,
                                                  u16* __restrict__ out, int n4) {
    int i = blockIdx.x * 256 + threadIdx.x;
    if (i >= n4) return;
    float4 v = ((const float4*)in)[i];
    uint2 o;
    o.x = (unsigned)f2b(v.x) | ((unsigned)f2b(v.y) << 16);
    o.y = (unsigned)f2b(v.z) | ((unsigned)f2b(v.w) << 16);
    ((uint2*)out)[i] = o;
}

// ---------- LayerNorm (C=512), fp32 in -> bf16 out ----------
__global__ __launch_bounds__(256) void ln_kernel(const float* __restrict__ x,
                                                 const float* __restrict__ w,
                                                 const float* __restrict__ b,
                                                 u16* __restrict__ out) {
    __shared__ float lds[8];
    int row = blockIdx.x;
    const float2* xr = (const float2*)(x + (size_t)row * 512);
    float2 v = xr[threadIdx.x];
    float s = v.x + v.y;
    float s2 = v.x * v.x + v.y * v.y;
    #pragma unroll
    for (int o = 32; o > 0; o >>= 1) {
        s += __shfl_down(s, o, 64);
        s2 += __shfl_down(s2, o, 64);
    }
    int wid = threadIdx.x >> 6, lane = threadIdx.x & 63;
    if (lane == 0) { lds[wid] = s; lds[4 + wid] = s2; }
    __syncthreads();
    s = lds[0] + lds[1] + lds[2] + lds[3];
    s2 = lds[4] + lds[5] + lds[6] + lds[7];
    float mu = s * (1.0f / 512.0f);
    float var = s2 * (1.0f / 512.0f) - mu * mu;
    float rstd = rsqrtf(var + 1e-5f);
    float2 wv = ((const float2*)w)[threadIdx.x];
    float2 bv = ((const float2*)b)[threadIdx.x];
    float o0 = (v.x - mu) * rstd * wv.x + bv.x;
    float o1 = (v.y - mu) * rstd * wv.y + bv.y;
    unsigned int pack = (unsigned)f2b(o0) | ((unsigned)f2b(o1) << 16);
    ((unsigned int*)(out + (size_t)row * 512))[threadIdx.x] = pack;
}

// ---------- bf16 MFMA GEMM: C[M,N] = A[M,K] @ W[N,K]^T + bias (+epilogue) ----------
// EPI: 0 = bias, store bf16          (qkv)
//      1 = bias + resid, store fp32  (proj)
//      2 = bias + GELU,  store bf16  (fc1)
//      3 = bias + resid, store fp32  (fc2 -> d_out)
template <int EPI>
__global__ __launch_bounds__(256) void gemm_bt(const u16* __restrict__ A,
                                               const u16* __restrict__ W,
                                               const float* __restrict__ bias,
                                               const float* __restrict__ resid,
                                               float* __restrict__ outF,
                                               u16* __restrict__ outB,
                                               int M, int Nn, int K) {
    int wid = threadIdx.x >> 6;
    int lane = threadIdx.x & 63;
    int wm = wid >> 1, wn = wid & 1;                 // 2x2 waves -> 128x128 block tile
    int m_wave = blockIdx.y * 128 + wm * 64;
    int n_wave = blockIdx.x * 128 + wn * 64;
    int lr = lane & 15;
    int lk = (lane >> 4) << 3;                       // k offset base (0,8,16,24)
    floatx4 acc[4][4];
    #pragma unroll
    for (int i = 0; i < 4; i++)
        #pragma unroll
        for (int j = 0; j < 4; j++) acc[i][j] = (floatx4){0.f, 0.f, 0.f, 0.f};

    const u16* Ab = A + (size_t)(m_wave + lr) * K + lk;
    const u16* Wb = W + (size_t)(n_wave + lr) * K + lk;

    for (int k0 = 0; k0 < K; k0 += 32) {
        shortx8 af[4], bf[4];
        #pragma unroll
        for (int i = 0; i < 4; i++)
            af[i] = *(const shortx8*)(Ab + (size_t)(i * 16) * K + k0);
        #pragma unroll
        for (int i = 0; i < 4; i++)
            bf[i] = *(const shortx8*)(Wb + (size_t)(i * 16) * K + k0);
        #pragma unroll
        for (int mi = 0; mi < 4; mi++)
            #pragma unroll
            for (int ni = 0; ni < 4; ni++)
                acc[mi][ni] = __builtin_amdgcn_mfma_f32_16x16x32_bf16(
                    af[mi], bf[ni], acc[mi][ni], 0, 0, 0);
    }

    // C/D layout (m89-verified): col = lane&15, row = (lane>>4)*4 + reg
    int col_l = lane & 15;
    int row_base = (lane >> 4) * 4;
    #pragma unroll
    for (int ni = 0; ni < 4; ni++) {
        int col = n_wave + ni * 16 + col_l;
        float bv = bias[col];
        #pragma unroll
        for (int mi = 0; mi < 4; mi++) {
            #pragma unroll
            for (int r = 0; r < 4; r++) {
                int row = m_wave + mi * 16 + row_base + r;
                size_t off = (size_t)row * Nn + col;
                float v = acc[mi][ni][r] + bv;
                if (EPI == 1 || EPI == 3) {
                    outF[off] = v + resid[off];
                } else if (EPI == 2) {
                    v = 0.5f * v * (1.0f + erff(v * 0.70710678118f));
                    outB[off] = f2b(v);
                } else {
                    outB[off] = f2b(v);
                }
            }
        }
    }
}

// ---------- windowed attention: one wave per (n,h,t) ----------
// qkv layout: row (n*T+t), col = s*512 + h*64 + d  (s=0:q, 1:k, 2:v), bf16
__global__ __launch_bounds__(256) void attn_kernel(const u16* __restrict__ qkv,
                                                   const float* __restrict__ rel_bias,
                                                   u16* __restrict__ out) {
    __shared__ float q_s[4][64];
    __shared__ float p_s[4][64];
    __shared__ float l_s[4];
    int wid = threadIdx.x >> 6, lane = threadIdx.x & 63;
    int gw = blockIdx.x * 4 + wid;        // 0 .. 32767
    int t = gw & 2047;
    int h = (gw >> 11) & 7;
    int n = gw >> 14;

    // stage q (scaled) into LDS
    size_t rowq = (size_t)(n * 2048 + t) * 1536 + (size_t)h * 64;
    q_s[wid][lane] = b2f(qkv[rowq + lane]) * 0.125f;   // scale = hd^-0.5
    __syncthreads();

    // phase 1: lane = window position w; dot(q, k[t+w-31])
    int pos = t + lane - 31;
    bool inb = (lane < 63) && (pos >= 0) && (pos < 2048);
    float acc = 0.f;
    if (inb) {
        const u16* krow = qkv + (size_t)(n * 2048 + pos) * 1536 + 512 + h * 64;
        #pragma unroll
        for (int d = 0; d < 64; d += 4) {
            uint2 kk = *(const uint2*)(krow + d);
            acc += q_s[wid][d + 0] * b2f((u16)(kk.x & 0xffffu));
            acc += q_s[wid][d + 1] * b2f((u16)(kk.x >> 16));
            acc += q_s[wid][d + 2] * b2f((u16)(kk.y & 0xffffu));
            acc += q_s[wid][d + 3] * b2f((u16)(kk.y >> 16));
        }
    }
    float s;
    if (lane >= 63) {
        s = -1e30f;                        // lane 63 excluded (WIN=63)
    } else {
        float bv = rel_bias[h * 63 + lane];
        s = inb ? (acc + bv) : (bv - 100.0f);   // matches ref: pad-dot=0 + bias + mask
    }
    float mx = s;
    #pragma unroll
    for (int o = 32; o > 0; o >>= 1) mx = fmaxf(mx, __shfl_xor(mx, o, 64));
    float pr = (lane < 63) ? expf(s - mx) : 0.f;
    float l = pr;
    #pragma unroll
    for (int o = 32; o > 0; o >>= 1) l += __shfl_xor(l, o, 64);
    p_s[wid][lane] = pr;
    if (lane == 0) l_s[wid] = l;
    __syncthreads();

    // phase 2: lane = d; out[d] = sum_w p[w] * v[t+w-31][d] / l   (coalesced v loads)
    float accv = 0.f;
    int w0 = 31 - t;          if (w0 < 0) w0 = 0;
    int w1 = 2048 - t + 31;   if (w1 > 63) w1 = 63;
    const u16* vcol = qkv + (size_t)n * 2048 * 1536 + 1024 + h * 64 + lane;
    for (int w = w0; w < w1; ++w) {
        int pv = t + w - 31;
        accv += p_s[wid][w] * b2f(vcol[(size_t)pv * 1536]);
    }
    out[(size_t)(n * 2048 + t) * 512 + h * 64 + lane] = f2b(accv / l_s[wid]);
}

// ---------- launcher ----------
extern "C" void kernel_launch(void* const* d_in, const int* in_sizes, int n_in,
                              void* d_out, int out_size, void* d_ws, size_t ws_size,
                              hipStream_t stream) {
    const float* x     = (const float*)d_in[0];
    const float* n1w   = (const float*)d_in[1];
    const float* n1b   = (const float*)d_in[2];
    const float* qkvw  = (const float*)d_in[3];
    const float* qkvbv = (const float*)d_in[4];
    const float* relb  = (const float*)d_in[5];
    const float* projw = (const float*)d_in[6];
    const float* projb = (const float*)d_in[7];
    const float* n2w   = (const float*)d_in[8];
    const float* n2b   = (const float*)d_in[9];
    const float* fc1w  = (const float*)d_in[10];
    const float* fc1b  = (const float*)d_in[11];
    const float* fc2w  = (const float*)d_in[12];
    const float* fc2b  = (const float*)d_in[13];
    float* out = (float*)d_out;

    // workspace layout (all 16B-aligned; total = 50 MiB)
    char* p = (char*)d_ws;
    u16* wq   = (u16*)p;  p += (size_t)786432 * 2;   // qkv_w bf16 (1536x512)
    u16* wp   = (u16*)p;  p += (size_t)262144 * 2;   // proj_w bf16 (512x512)
    u16* w1   = (u16*)p;  p += (size_t)1048576 * 2;  // fc1_w bf16 (2048x512)
    u16* w2   = (u16*)p;  p += (size_t)1048576 * 2;  // fc2_w bf16 (512x2048)
    u16* hb   = (u16*)p;  p += (size_t)2097152 * 2;  // h / h2 bf16 (4096x512)
    u16* qkvb = (u16*)p;  p += (size_t)6291456 * 2;  // qkv bf16 (4096x1536)
    u16* attb = (u16*)p;  p += (size_t)2097152 * 2;  // attn out bf16 (4096x512)
    float* x2 = (float*)p; p += (size_t)2097152 * 4; // x + proj(attn) fp32 (4096x512)
    u16* mb   = (u16*)p;  p += (size_t)8388608 * 2;  // gelu(fc1) bf16 (4096x2048)

    // weight conversions (inputs re-poisoned every call -> reconvert every call)
    cvt_kernel<<<768, 256, 0, stream>>>(qkvw, wq, 786432 / 4);
    cvt_kernel<<<256, 256, 0, stream>>>(projw, wp, 262144 / 4);
    cvt_kernel<<<1024, 256, 0, stream>>>(fc1w, w1, 1048576 / 4);
    cvt_kernel<<<1024, 256, 0, stream>>>(fc2w, w2, 1048576 / 4);

    // LN1
    ln_kernel<<<4096, 256, 0, stream>>>(x, n1w, n1b, hb);
    // qkv = h @ qkv_w^T + b   (4096x512 @ 512x1536)
    gemm_bt<0><<<dim3(12, 32), 256, 0, stream>>>(hb, wq, qkvbv, nullptr, nullptr,
                                                 qkvb, 4096, 1536, 512);
    // windowed attention
    attn_kernel<<<8192, 256, 0, stream>>>(qkvb, relb, attb);
    // x2 = x + attn @ proj_w^T + b
    gemm_bt<1><<<dim3(4, 32), 256, 0, stream>>>(attb, wp, projb, x, x2, nullptr,
                                                4096, 512, 512);
    // LN2
    ln_kernel<<<4096, 256, 0, stream>>>(x2, n2w, n2b, hb);
    // m = gelu(h2 @ fc1_w^T + b)
    gemm_bt<2><<<dim3(16, 32), 256, 0, stream>>>(hb, w1, fc1b, nullptr, nullptr,
                                                 mb, 4096, 2048, 512);
    // out = x2 + m @ fc2_w^T + b
    gemm_bt<3><<<dim3(4, 32), 256, 0, stream>>>(mb, w2, fc2b, x2, out, nullptr,
                                                4096, 512, 2048);
}

// Round 2
// 321.312 us; speedup vs baseline: 1.1890x; 1.1890x over previous
//
#include <hip/hip_runtime.h>

typedef unsigned short u16;
typedef unsigned int uint;
typedef __attribute__((ext_vector_type(4))) float floatx4;
typedef __attribute__((ext_vector_type(8))) short shortx8;

// ---------- helpers ----------
__device__ __forceinline__ u16 f2b(float f) {
    unsigned int u = __float_as_uint(f);
    unsigned int r = (u + 0x7fffu + ((u >> 16) & 1u)) >> 16;
    return (u16)r;
}
__device__ __forceinline__ float b2f(u16 u) {
    return __uint_as_float(((unsigned int)u) << 16);
}
__device__ __forceinline__ float blo(uint u) { return __uint_as_float(u << 16); }
__device__ __forceinline__ float bhi(uint u) { return __uint_as_float(u & 0xffff0000u); }

// ---------- fp32 -> bf16 conversion (weights) ----------
__global__ __launch_bounds__(256) void cvt_kernel(const float* __restrict__ in,
                                                  u16* __restrict__ out, int n4) {
    int i = blockIdx.x * 256 + threadIdx.x;
    if (i >= n4) return;
    float4 v = ((const float4*)in)[i];
    uint2 o;
    o.x = (unsigned)f2b(v.x) | ((unsigned)f2b(v.y) << 16);
    o.y = (unsigned)f2b(v.z) | ((unsigned)f2b(v.w) << 16);
    ((uint2*)out)[i] = o;
}

// ---------- LayerNorm (C=512), fp32 in -> bf16 out ----------
__global__ __launch_bounds__(256) void ln_kernel(const float* __restrict__ x,
                                                 const float* __restrict__ w,
                                                 const float* __restrict__ b,
                                                 u16* __restrict__ out) {
    __shared__ float lds[8];
    int row = blockIdx.x;
    const float2* xr = (const float2*)(x + (size_t)row * 512);
    float2 v = xr[threadIdx.x];
    float s = v.x + v.y;
    float s2 = v.x * v.x + v.y * v.y;
    #pragma unroll
    for (int o = 32; o > 0; o >>= 1) {
        s += __shfl_down(s, o, 64);
        s2 += __shfl_down(s2, o, 64);
    }
    int wid = threadIdx.x >> 6, lane = threadIdx.x & 63;
    if (lane == 0) { lds[wid] = s; lds[4 + wid] = s2; }
    __syncthreads();
    s = lds[0] + lds[1] + lds[2] + lds[3];
    s2 = lds[4] + lds[5] + lds[6] + lds[7];
    float mu = s * (1.0f / 512.0f);
    float var = s2 * (1.0f / 512.0f) - mu * mu;
    float rstd = rsqrtf(var + 1e-5f);
    float2 wv = ((const float2*)w)[threadIdx.x];
    float2 bv = ((const float2*)b)[threadIdx.x];
    float o0 = (v.x - mu) * rstd * wv.x + bv.x;
    float o1 = (v.y - mu) * rstd * wv.y + bv.y;
    unsigned int pack = (unsigned)f2b(o0) | ((unsigned)f2b(o1) << 16);
    ((unsigned int*)(out + (size_t)row * 512))[threadIdx.x] = pack;
}

// ---------- bf16 MFMA GEMM: C[M,N] = A[M,K] @ W[N,K]^T + bias (+epilogue) ----------
template <int EPI>
__global__ __launch_bounds__(256) void gemm_bt(const u16* __restrict__ A,
                                               const u16* __restrict__ W,
                                               const float* __restrict__ bias,
                                               const float* __restrict__ resid,
                                               float* __restrict__ outF,
                                               u16* __restrict__ outB,
                                               int M, int Nn, int K) {
    int wid = threadIdx.x >> 6;
    int lane = threadIdx.x & 63;
    int wm = wid >> 1, wn = wid & 1;
    int m_wave = blockIdx.y * 128 + wm * 64;
    int n_wave = blockIdx.x * 128 + wn * 64;
    int lr = lane & 15;
    int lk = (lane >> 4) << 3;
    floatx4 acc[4][4];
    #pragma unroll
    for (int i = 0; i < 4; i++)
        #pragma unroll
        for (int j = 0; j < 4; j++) acc[i][j] = (floatx4){0.f, 0.f, 0.f, 0.f};

    const u16* Ab = A + (size_t)(m_wave + lr) * K + lk;
    const u16* Wb = W + (size_t)(n_wave + lr) * K + lk;

    for (int k0 = 0; k0 < K; k0 += 32) {
        shortx8 af[4], bf[4];
        #pragma unroll
        for (int i = 0; i < 4; i++)
            af[i] = *(const shortx8*)(Ab + (size_t)(i * 16) * K + k0);
        #pragma unroll
        for (int i = 0; i < 4; i++)
            bf[i] = *(const shortx8*)(Wb + (size_t)(i * 16) * K + k0);
        #pragma unroll
        for (int mi = 0; mi < 4; mi++)
            #pragma unroll
            for (int ni = 0; ni < 4; ni++)
                acc[mi][ni] = __builtin_amdgcn_mfma_f32_16x16x32_bf16(
                    af[mi], bf[ni], acc[mi][ni], 0, 0, 0);
    }

    int col_l = lane & 15;
    int row_base = (lane >> 4) * 4;
    #pragma unroll
    for (int ni = 0; ni < 4; ni++) {
        int col = n_wave + ni * 16 + col_l;
        float bv = bias[col];
        #pragma unroll
        for (int mi = 0; mi < 4; mi++) {
            #pragma unroll
            for (int r = 0; r < 4; r++) {
                int row = m_wave + mi * 16 + row_base + r;
                size_t off = (size_t)row * Nn + col;
                float v = acc[mi][ni][r] + bv;
                if (EPI == 1 || EPI == 3) {
                    outF[off] = v + resid[off];
                } else if (EPI == 2) {
                    v = 0.5f * v * (1.0f + erff(v * 0.70710678118f));
                    outB[off] = f2b(v);
                } else {
                    outB[off] = f2b(v);
                }
            }
        }
    }
}

// ---------- windowed attention, LDS-staged ----------
// One block per (n, h, 64-wide t-tile). 512 blocks.
// qkv bf16, row (n*T+t), col = s*512 + h*64 + d. Staged K/V window + Q tile in LDS.
__global__ __launch_bounds__(256) void attn_kernel(const u16* __restrict__ qkv,
                                                   const float* __restrict__ rel_bias,
                                                   u16* __restrict__ out) {
    // rows padded to 33 uints (66 bf16): phase1 k-reads 2-way bank alias (free),
    // phase2 v-reads conflict-free.
    __shared__ uint k_s[128 * 33];
    __shared__ uint v_s[128 * 33];
    __shared__ uint q_s[64 * 33];

    int bx = blockIdx.x;
    int n = bx >> 8;
    int h = (bx >> 5) & 7;
    int t0 = (bx & 31) << 6;

    const uint* qkv_u = (const uint*)qkv;  // row pitch 768 uints

    // stage K,V rows 0..127 (pos = t0-31+row), zero-filled OOB; coalesced.
    for (int idx = threadIdx.x; idx < 128 * 32; idx += 256) {
        int row = idx >> 5, j = idx & 31;
        int pos = t0 - 31 + row;
        uint kv = 0, vv = 0;
        if (pos >= 0 && pos < 2048) {
            size_t base = (size_t)(n * 2048 + pos) * 768 + h * 32 + j;
            kv = qkv_u[base + 256];
            vv = qkv_u[base + 512];
        }
        k_s[row * 33 + j] = kv;
        v_s[row * 33 + j] = vv;
    }
    // stage Q tile (always in range)
    for (int idx = threadIdx.x; idx < 64 * 32; idx += 256) {
        int row = idx >> 5, j = idx & 31;
        size_t base = (size_t)(n * 2048 + t0 + row) * 768 + h * 32 + j;
        q_s[row * 33 + j] = qkv_u[base];
    }
    __syncthreads();

    int wid = threadIdx.x >> 6, lane = threadIdx.x & 63;
    float bias_l = (lane < 63) ? rel_bias[h * 63 + lane] : 0.f;

    for (int i = 0; i < 16; i++) {
        int tr = wid * 16 + i;          // t - t0
        int t = t0 + tr;

        // phase 1: lane = window position w; dot(q[t], k[t+w-31]) from LDS
        const uint* kr = k_s + (tr + lane) * 33;
        const uint* qr = q_s + tr * 33;
        float acc = 0.f;
        #pragma unroll
        for (int j = 0; j < 32; j++) {
            uint ku = kr[j], qu = qr[j];
            acc += blo(qu) * blo(ku);
            acc += bhi(qu) * bhi(ku);
        }
        int pos = t + lane - 31;
        bool inb = (pos >= 0) && (pos < 2048);
        float s = acc * 0.125f + bias_l;
        if (!inb) s -= 100.f;
        if (lane == 63) s = -1e30f;

        float mx = s;
        #pragma unroll
        for (int o = 32; o > 0; o >>= 1) mx = fmaxf(mx, __shfl_xor(mx, o, 64));
        float pr = expf(s - mx);        // lane63 -> 0
        float l = pr;
        #pragma unroll
        for (int o = 32; o > 0; o >>= 1) l += __shfl_xor(l, o, 64);

        // phase 2: lane = d; out[d] = sum_w p[w] * v[tr+w][d] / l
        float accv = 0.f;
        const uint* vb = v_s + tr * 33 + (lane >> 1);
        #pragma unroll
        for (int w = 0; w < 63; w++) {
            float pw = __shfl(pr, w, 64);    // literal idx -> v_readlane (sgpr)
            uint vu = vb[w * 33];
            float vv = __uint_as_float((lane & 1) ? (vu & 0xffff0000u) : (vu << 16));
            accv += pw * vv;
        }
        out[(size_t)(n * 2048 + t) * 512 + h * 64 + lane] = f2b(accv / l);
    }
}

// ---------- launcher ----------
extern "C" void kernel_launch(void* const* d_in, const int* in_sizes, int n_in,
                              void* d_out, int out_size, void* d_ws, size_t ws_size,
                              hipStream_t stream) {
    const float* x     = (const float*)d_in[0];
    const float* n1w   = (const float*)d_in[1];
    const float* n1b   = (const float*)d_in[2];
    const float* qkvw  = (const float*)d_in[3];
    const float* qkvbv = (const float*)d_in[4];
    const float* relb  = (const float*)d_in[5];
    const float* projw = (const float*)d_in[6];
    const float* projb = (const float*)d_in[7];
    const float* n2w   = (const float*)d_in[8];
    const float* n2b   = (const float*)d_in[9];
    const float* fc1w  = (const float*)d_in[10];
    const float* fc1b  = (const float*)d_in[11];
    const float* fc2w  = (const float*)d_in[12];
    const float* fc2b  = (const float*)d_in[13];
    float* out = (float*)d_out;

    char* p = (char*)d_ws;
    u16* wq   = (u16*)p;  p += (size_t)786432 * 2;   // qkv_w bf16 (1536x512)
    u16* wp   = (u16*)p;  p += (size_t)262144 * 2;   // proj_w bf16 (512x512)
    u16* w1   = (u16*)p;  p += (size_t)1048576 * 2;  // fc1_w bf16 (2048x512)
    u16* w2   = (u16*)p;  p += (size_t)1048576 * 2;  // fc2_w bf16 (512x2048)
    u16* hb   = (u16*)p;  p += (size_t)2097152 * 2;  // h / h2 bf16 (4096x512)
    u16* qkvb = (u16*)p;  p += (size_t)6291456 * 2;  // qkv bf16 (4096x1536)
    u16* attb = (u16*)p;  p += (size_t)2097152 * 2;  // attn out bf16 (4096x512)
    float* x2 = (float*)p; p += (size_t)2097152 * 4; // x + proj(attn) fp32 (4096x512)
    u16* mb   = (u16*)p;  p += (size_t)8388608 * 2;  // gelu(fc1) bf16 (4096x2048)

    cvt_kernel<<<768, 256, 0, stream>>>(qkvw, wq, 786432 / 4);
    cvt_kernel<<<256, 256, 0, stream>>>(projw, wp, 262144 / 4);
    cvt_kernel<<<1024, 256, 0, stream>>>(fc1w, w1, 1048576 / 4);
    cvt_kernel<<<1024, 256, 0, stream>>>(fc2w, w2, 1048576 / 4);

    ln_kernel<<<4096, 256, 0, stream>>>(x, n1w, n1b, hb);
    gemm_bt<0><<<dim3(12, 32), 256, 0, stream>>>(hb, wq, qkvbv, nullptr, nullptr,
                                                 qkvb, 4096, 1536, 512);
    attn_kernel<<<512, 256, 0, stream>>>(qkvb, relb, attb);
    gemm_bt<1><<<dim3(4, 32), 256, 0, stream>>>(attb, wp, projb, x, x2, nullptr,
                                                4096, 512, 512);
    ln_kernel<<<4096, 256, 0, stream>>>(x2, n2w, n2b, hb);
    gemm_bt<2><<<dim3(16, 32), 256, 0, stream>>>(hb, w1, fc1b, nullptr, nullptr,
                                                 mb, 4096, 2048, 512);
    gemm_bt<3><<<dim3(4, 32), 256, 0, stream>>>(mb, w2, fc2b, x2, out, nullptr,
                                                4096, 512, 2048);
}

// Round 3
// 271.824 us; speedup vs baseline: 1.4055x; 1.1821x over previous
//
#include <hip/hip_runtime.h>

typedef unsigned short u16;
typedef unsigned int uint;
typedef __attribute__((ext_vector_type(4))) float floatx4;
typedef __attribute__((ext_vector_type(8))) short shortx8;

// ---------- helpers ----------
__device__ __forceinline__ u16 f2b(float f) {
    unsigned int u = __float_as_uint(f);
    unsigned int r = (u + 0x7fffu + ((u >> 16) & 1u)) >> 16;
    return (u16)r;
}
__device__ __forceinline__ float b2f(u16 u) {
    return __uint_as_float(((unsigned int)u) << 16);
}

// ---------- fp32 -> bf16 conversion (weights) ----------
__global__ __launch_bounds__(256) void cvt_kernel(const float* __restrict__ in,
                                                  u16* __restrict__ out, int n4) {
    int i = blockIdx.x * 256 + threadIdx.x;
    if (i >= n4) return;
    float4 v = ((const float4*)in)[i];
    uint2 o;
    o.x = (unsigned)f2b(v.x) | ((unsigned)f2b(v.y) << 16);
    o.y = (unsigned)f2b(v.z) | ((unsigned)f2b(v.w) << 16);
    ((uint2*)out)[i] = o;
}

// ---------- LayerNorm (C=512), fp32 in -> bf16 out ----------
__global__ __launch_bounds__(256) void ln_kernel(const float* __restrict__ x,
                                                 const float* __restrict__ w,
                                                 const float* __restrict__ b,
                                                 u16* __restrict__ out) {
    __shared__ float lds[8];
    int row = blockIdx.x;
    const float2* xr = (const float2*)(x + (size_t)row * 512);
    float2 v = xr[threadIdx.x];
    float s = v.x + v.y;
    float s2 = v.x * v.x + v.y * v.y;
    #pragma unroll
    for (int o = 32; o > 0; o >>= 1) {
        s += __shfl_down(s, o, 64);
        s2 += __shfl_down(s2, o, 64);
    }
    int wid = threadIdx.x >> 6, lane = threadIdx.x & 63;
    if (lane == 0) { lds[wid] = s; lds[4 + wid] = s2; }
    __syncthreads();
    s = lds[0] + lds[1] + lds[2] + lds[3];
    s2 = lds[4] + lds[5] + lds[6] + lds[7];
    float mu = s * (1.0f / 512.0f);
    float var = s2 * (1.0f / 512.0f) - mu * mu;
    float rstd = rsqrtf(var + 1e-5f);
    float2 wv = ((const float2*)w)[threadIdx.x];
    float2 bv = ((const float2*)b)[threadIdx.x];
    float o0 = (v.x - mu) * rstd * wv.x + bv.x;
    float o1 = (v.y - mu) * rstd * wv.y + bv.y;
    unsigned int pack = (unsigned)f2b(o0) | ((unsigned)f2b(o1) << 16);
    ((unsigned int*)(out + (size_t)row * 512))[threadIdx.x] = pack;
}

// ---------- bf16 MFMA GEMM: C[M,N] = A[M,K] @ W[N,K]^T + bias (+epilogue) ----------
template <int EPI>
__global__ __launch_bounds__(256) void gemm_bt(const u16* __restrict__ A,
                                               const u16* __restrict__ W,
                                               const float* __restrict__ bias,
                                               const float* __restrict__ resid,
                                               float* __restrict__ outF,
                                               u16* __restrict__ outB,
                                               int M, int Nn, int K) {
    int wid = threadIdx.x >> 6;
    int lane = threadIdx.x & 63;
    int wm = wid >> 1, wn = wid & 1;
    int m_wave = blockIdx.y * 128 + wm * 64;
    int n_wave = blockIdx.x * 128 + wn * 64;
    int lr = lane & 15;
    int lk = (lane >> 4) << 3;
    floatx4 acc[4][4];
    #pragma unroll
    for (int i = 0; i < 4; i++)
        #pragma unroll
        for (int j = 0; j < 4; j++) acc[i][j] = (floatx4){0.f, 0.f, 0.f, 0.f};

    const u16* Ab = A + (size_t)(m_wave + lr) * K + lk;
    const u16* Wb = W + (size_t)(n_wave + lr) * K + lk;

    for (int k0 = 0; k0 < K; k0 += 32) {
        shortx8 af[4], bf[4];
        #pragma unroll
        for (int i = 0; i < 4; i++)
            af[i] = *(const shortx8*)(Ab + (size_t)(i * 16) * K + k0);
        #pragma unroll
        for (int i = 0; i < 4; i++)
            bf[i] = *(const shortx8*)(Wb + (size_t)(i * 16) * K + k0);
        #pragma unroll
        for (int mi = 0; mi < 4; mi++)
            #pragma unroll
            for (int ni = 0; ni < 4; ni++)
                acc[mi][ni] = __builtin_amdgcn_mfma_f32_16x16x32_bf16(
                    af[mi], bf[ni], acc[mi][ni], 0, 0, 0);
    }

    int col_l = lane & 15;
    int row_base = (lane >> 4) * 4;
    #pragma unroll
    for (int ni = 0; ni < 4; ni++) {
        int col = n_wave + ni * 16 + col_l;
        float bv = bias[col];
        #pragma unroll
        for (int mi = 0; mi < 4; mi++) {
            #pragma unroll
            for (int r = 0; r < 4; r++) {
                int row = m_wave + mi * 16 + row_base + r;
                size_t off = (size_t)row * Nn + col;
                float v = acc[mi][ni][r] + bv;
                if (EPI == 1 || EPI == 3) {
                    outF[off] = v + resid[off];
                } else if (EPI == 2) {
                    v = 0.5f * v * (1.0f + erff(v * 0.70710678118f));
                    outB[off] = f2b(v);
                } else {
                    outB[off] = f2b(v);
                }
            }
        }
    }
}

// ---------- windowed attention, MFMA flash-style ----------
// One block per (n, h, 64-t tile); 4 waves x 16 t-rows. qkv bf16 row pitch 1536.
// Band of absolute key positions per wave: local pos wid*16 + [0,80); P[16][96]
// (cols 80..95 zeroed) @ V via 3 K-tiles of mfma_16x16x32.
__global__ __launch_bounds__(256) void attn_kernel(const u16* __restrict__ qkv,
                                                   const float* __restrict__ rel_bias,
                                                   u16* __restrict__ out) {
    __shared__ u16 k_s[128][72];     // [local pos][d]   18.4 KB (pitch 72: 2-way banks, 16B-aligned rows)
    __shared__ u16 v_t[64][152];     // [d][local pos]   19.5 KB (transposed V)
    __shared__ u16 p_s[4][16][104];  // per-wave P       13.3 KB
    __shared__ float s_bias[64];

    int bx = blockIdx.x;
    int n = bx >> 8;
    int h = (bx >> 5) & 7;
    int t0 = (bx & 31) << 6;
    int tid = threadIdx.x, wid = tid >> 6, lane = tid & 63;
    int col = lane & 15, rq = lane >> 4;

    // Q A-frags straight from global (L2-hot): A[m=col][k=rq*8+j], K=64 -> 2 frags
    const u16* qrow = qkv + (size_t)(n * 2048 + t0 + wid * 16 + col) * 1536 + h * 64 + rq * 8;
    shortx8 qf0 = *(const shortx8*)qrow;
    shortx8 qf1 = *(const shortx8*)(qrow + 32);

    if (tid < 63) s_bias[tid] = rel_bias[h * 63 + tid];
    if (tid == 63) s_bias[63] = 0.f;

    const uint* qkv_u = (const uint*)qkv;  // row pitch 768 uints
    // stage K rows (local pos 0..127), zero OOB; coalesced
    for (int idx = tid; idx < 128 * 32; idx += 256) {
        int row = idx >> 5, j = idx & 31;
        int pos = t0 - 31 + row;
        uint kv = 0;
        if (pos >= 0 && pos < 2048)
            kv = qkv_u[(size_t)(n * 2048 + pos) * 768 + 256 + h * 32 + j];
        *(uint*)&k_s[row][j * 2] = kv;
    }
    // stage V rows 0..143 transposed, zero OOB
    for (int idx = tid; idx < 144 * 32; idx += 256) {
        int row = idx >> 5, j = idx & 31;
        int pos = t0 - 31 + row;
        uint vv = 0;
        if (pos >= 0 && pos < 2048)
            vv = qkv_u[(size_t)(n * 2048 + pos) * 768 + 512 + h * 32 + j];
        v_t[2 * j][row] = (u16)(vv & 0xffffu);
        v_t[2 * j + 1][row] = (u16)(vv >> 16);
    }
    __syncthreads();

    // ---- QK^T: S[16][80] as 5 N-tiles ----
    floatx4 S[5];
    #pragma unroll
    for (int nt = 0; nt < 5; nt++) S[nt] = (floatx4){0.f, 0.f, 0.f, 0.f};
    #pragma unroll
    for (int nt = 0; nt < 5; nt++) {
        const u16* kb = &k_s[wid * 16 + nt * 16 + col][rq * 8];
        shortx8 b0 = *(const shortx8*)kb;
        shortx8 b1 = *(const shortx8*)(kb + 32);
        S[nt] = __builtin_amdgcn_mfma_f32_16x16x32_bf16(qf0, b0, S[nt], 0, 0, 0);
        S[nt] = __builtin_amdgcn_mfma_f32_16x16x32_bf16(qf1, b1, S[nt], 0, 0, 0);
    }

    // ---- softmax per row (C layout: row = rq*4+r, col = lane&15) ----
    #pragma unroll
    for (int r = 0; r < 4; r++) {
        int t_row = rq * 4 + r;
        float sc[5];
        float mx = -1e30f;
        #pragma unroll
        for (int nt = 0; nt < 5; nt++) {
            int w = nt * 16 + col - t_row;
            int pos_abs = t0 - 31 + wid * 16 + nt * 16 + col;
            float v;
            if (w < 0 || w > 62) {
                v = -1e30f;
            } else {
                v = S[nt][r] * 0.125f + s_bias[w];
                if (pos_abs < 0 || pos_abs >= 2048) v -= 100.f;
            }
            sc[nt] = v;
            mx = fmaxf(mx, v);
        }
        #pragma unroll
        for (int o = 1; o < 16; o <<= 1) mx = fmaxf(mx, __shfl_xor(mx, o, 64));
        float l = 0.f;
        #pragma unroll
        for (int nt = 0; nt < 5; nt++) {
            sc[nt] = __expf(sc[nt] - mx);
            l += sc[nt];
        }
        #pragma unroll
        for (int o = 1; o < 16; o <<= 1) l += __shfl_xor(l, o, 64);
        float inv = 1.0f / l;
        #pragma unroll
        for (int nt = 0; nt < 5; nt++)
            p_s[wid][t_row][nt * 16 + col] = f2b(sc[nt] * inv);
        p_s[wid][t_row][80 + col] = 0;   // zero pad cols 80..95
    }
    __syncthreads();

    // ---- PV: O[16][64] = P[16][96] @ V[96][64] ----
    floatx4 O[4];
    #pragma unroll
    for (int dt = 0; dt < 4; dt++) O[dt] = (floatx4){0.f, 0.f, 0.f, 0.f};
    const u16* pr = &p_s[wid][col][rq * 8];
    shortx8 a0 = *(const shortx8*)pr;
    shortx8 a1 = *(const shortx8*)(pr + 32);
    shortx8 a2 = *(const shortx8*)(pr + 64);
    #pragma unroll
    for (int dt = 0; dt < 4; dt++) {
        const u16* vb = &v_t[dt * 16 + col][wid * 16 + rq * 8];
        shortx8 b0 = *(const shortx8*)vb;
        shortx8 b1 = *(const shortx8*)(vb + 32);
        shortx8 b2 = *(const shortx8*)(vb + 64);
        O[dt] = __builtin_amdgcn_mfma_f32_16x16x32_bf16(a0, b0, O[dt], 0, 0, 0);
        O[dt] = __builtin_amdgcn_mfma_f32_16x16x32_bf16(a1, b1, O[dt], 0, 0, 0);
        O[dt] = __builtin_amdgcn_mfma_f32_16x16x32_bf16(a2, b2, O[dt], 0, 0, 0);
    }

    // ---- epilogue: C layout scatter (bf16) ----
    #pragma unroll
    for (int dt = 0; dt < 4; dt++) {
        #pragma unroll
        for (int r = 0; r < 4; r++) {
            int t_row = rq * 4 + r;
            out[(size_t)(n * 2048 + t0 + wid * 16 + t_row) * 512 + h * 64 + dt * 16 + col] =
                f2b(O[dt][r]);
        }
    }
}

// ---------- launcher ----------
extern "C" void kernel_launch(void* const* d_in, const int* in_sizes, int n_in,
                              void* d_out, int out_size, void* d_ws, size_t ws_size,
                              hipStream_t stream) {
    const float* x     = (const float*)d_in[0];
    const float* n1w   = (const float*)d_in[1];
    const float* n1b   = (const float*)d_in[2];
    const float* qkvw  = (const float*)d_in[3];
    const float* qkvbv = (const float*)d_in[4];
    const float* relb  = (const float*)d_in[5];
    const float* projw = (const float*)d_in[6];
    const float* projb = (const float*)d_in[7];
    const float* n2w   = (const float*)d_in[8];
    const float* n2b   = (const float*)d_in[9];
    const float* fc1w  = (const float*)d_in[10];
    const float* fc1b  = (const float*)d_in[11];
    const float* fc2w  = (const float*)d_in[12];
    const float* fc2b  = (const float*)d_in[13];
    float* out = (float*)d_out;

    char* p = (char*)d_ws;
    u16* wq   = (u16*)p;  p += (size_t)786432 * 2;   // qkv_w bf16 (1536x512)
    u16* wp   = (u16*)p;  p += (size_t)262144 * 2;   // proj_w bf16 (512x512)
    u16* w1   = (u16*)p;  p += (size_t)1048576 * 2;  // fc1_w bf16 (2048x512)
    u16* w2   = (u16*)p;  p += (size_t)1048576 * 2;  // fc2_w bf16 (512x2048)
    u16* hb   = (u16*)p;  p += (size_t)2097152 * 2;  // h / h2 bf16 (4096x512)
    u16* qkvb = (u16*)p;  p += (size_t)6291456 * 2;  // qkv bf16 (4096x1536)
    u16* attb = (u16*)p;  p += (size_t)2097152 * 2;  // attn out bf16 (4096x512)
    float* x2 = (float*)p; p += (size_t)2097152 * 4; // x + proj(attn) fp32 (4096x512)
    u16* mb   = (u16*)p;  p += (size_t)8388608 * 2;  // gelu(fc1) bf16 (4096x2048)

    cvt_kernel<<<768, 256, 0, stream>>>(qkvw, wq, 786432 / 4);
    cvt_kernel<<<256, 256, 0, stream>>>(projw, wp, 262144 / 4);
    cvt_kernel<<<1024, 256, 0, stream>>>(fc1w, w1, 1048576 / 4);
    cvt_kernel<<<1024, 256, 0, stream>>>(fc2w, w2, 1048576 / 4);

    ln_kernel<<<4096, 256, 0, stream>>>(x, n1w, n1b, hb);
    gemm_bt<0><<<dim3(12, 32), 256, 0, stream>>>(hb, wq, qkvbv, nullptr, nullptr,
                                                 qkvb, 4096, 1536, 512);
    attn_kernel<<<512, 256, 0, stream>>>(qkvb, relb, attb);
    gemm_bt<1><<<dim3(4, 32), 256, 0, stream>>>(attb, wp, projb, x, x2, nullptr,
                                                4096, 512, 512);
    ln_kernel<<<4096, 256, 0, stream>>>(x2, n2w, n2b, hb);
    gemm_bt<2><<<dim3(16, 32), 256, 0, stream>>>(hb, w1, fc1b, nullptr, nullptr,
                                                 mb, 4096, 2048, 512);
    gemm_bt<3><<<dim3(4, 32), 256, 0, stream>>>(mb, w2, fc2b, x2, out, nullptr,
                                                4096, 512, 2048);
}

// Round 4
// 205.975 us; speedup vs baseline: 1.8548x; 1.3197x over previous
//
#include <hip/hip_runtime.h>

typedef unsigned short u16;
typedef unsigned int uint;
typedef __attribute__((ext_vector_type(4))) float floatx4;
typedef __attribute__((ext_vector_type(8))) short shortx8;

// ---------- helpers ----------
__device__ __forceinline__ u16 f2b(float f) {
    unsigned int u = __float_as_uint(f);
    unsigned int r = (u + 0x7fffu + ((u >> 16) & 1u)) >> 16;
    return (u16)r;
}
__device__ __forceinline__ float b2f(u16 u) {
    return __uint_as_float(((unsigned int)u) << 16);
}
__device__ __forceinline__ void gl_lds16(const u16* g, u16* l) {
    __builtin_amdgcn_global_load_lds(
        (const __attribute__((address_space(1))) void*)g,
        (__attribute__((address_space(3))) void*)l, 16, 0, 0);
}

// ---------- fp32 -> bf16 conversion (weights) ----------
__global__ __launch_bounds__(256) void cvt_kernel(const float* __restrict__ in,
                                                  u16* __restrict__ out, int n4) {
    int i = blockIdx.x * 256 + threadIdx.x;
    if (i >= n4) return;
    float4 v = ((const float4*)in)[i];
    uint2 o;
    o.x = (unsigned)f2b(v.x) | ((unsigned)f2b(v.y) << 16);
    o.y = (unsigned)f2b(v.z) | ((unsigned)f2b(v.w) << 16);
    ((uint2*)out)[i] = o;
}

// ---------- LayerNorm (C=512), fp32 in -> bf16 out ----------
__global__ __launch_bounds__(256) void ln_kernel(const float* __restrict__ x,
                                                 const float* __restrict__ w,
                                                 const float* __restrict__ b,
                                                 u16* __restrict__ out) {
    __shared__ float lds[8];
    int row = blockIdx.x;
    const float2* xr = (const float2*)(x + (size_t)row * 512);
    float2 v = xr[threadIdx.x];
    float s = v.x + v.y;
    float s2 = v.x * v.x + v.y * v.y;
    #pragma unroll
    for (int o = 32; o > 0; o >>= 1) {
        s += __shfl_down(s, o, 64);
        s2 += __shfl_down(s2, o, 64);
    }
    int wid = threadIdx.x >> 6, lane = threadIdx.x & 63;
    if (lane == 0) { lds[wid] = s; lds[4 + wid] = s2; }
    __syncthreads();
    s = lds[0] + lds[1] + lds[2] + lds[3];
    s2 = lds[4] + lds[5] + lds[6] + lds[7];
    float mu = s * (1.0f / 512.0f);
    float var = s2 * (1.0f / 512.0f) - mu * mu;
    float rstd = rsqrtf(var + 1e-5f);
    float2 wv = ((const float2*)w)[threadIdx.x];
    float2 bv = ((const float2*)b)[threadIdx.x];
    float o0 = (v.x - mu) * rstd * wv.x + bv.x;
    float o1 = (v.y - mu) * rstd * wv.y + bv.y;
    unsigned int pack = (unsigned)f2b(o0) | ((unsigned)f2b(o1) << 16);
    ((unsigned int*)(out + (size_t)row * 512))[threadIdx.x] = pack;
}

// ---------- bf16 MFMA GEMM, m97-style LDS staging ----------
// C[M,N] = A[M,K] @ W[N,K]^T + bias (+epilogue). BK=64.
// LDS layout: 16B chunks, chunk(row, kc) stored at row*8 + (kc ^ (row&7))
// -> staging coalesced (128B/row permuted), frag ds_read_b128 2-way aliased (free).
// EPI: 0 = bias, store bf16 (qkv) | 1 = bias+resid, fp32 (proj)
//      2 = bias+GELU, bf16 (fc1)  | 3 = bias+resid, fp32 (fc2 -> d_out)
template <int BM, int BN, int EPI>
__global__ __launch_bounds__(256) void gemm_lds(const u16* __restrict__ A,
                                                const u16* __restrict__ W,
                                                const float* __restrict__ bias,
                                                const float* __restrict__ resid,
                                                float* __restrict__ outF,
                                                u16* __restrict__ outB,
                                                int M, int Nn, int K) {
    constexpr int MI = BM / 32;          // A-frags per wave
    constexpr int NI = BN / 32;          // B-frags per wave
    __shared__ u16 a_s[BM * 64];
    __shared__ u16 b_s[BN * 64];

    int tid = threadIdx.x;
    int wid = tid >> 6, lane = tid & 63;
    int wm = wid >> 1, wn = wid & 1;     // 2x2 waves
    int m_blk = blockIdx.y * BM;
    int n_blk = blockIdx.x * BN;
    int lr = lane & 15;
    int lkc = lane >> 4;                 // k-chunk 0..3 within 32-k sub-tile

    floatx4 acc[MI][NI];
    #pragma unroll
    for (int i = 0; i < MI; i++)
        #pragma unroll
        for (int j = 0; j < NI; j++) acc[i][j] = (floatx4){0.f, 0.f, 0.f, 0.f};

    const u16* Ag = A + (size_t)m_blk * K;
    const u16* Wg = W + (size_t)n_blk * K;

    for (int k0 = 0; k0 < K; k0 += 64) {
        #pragma unroll
        for (int p = 0; p < BM * 8 / 256; p++) {
            int c = p * 256 + tid;
            int row = c >> 3;
            int kc = (c & 7) ^ (row & 7);
            gl_lds16(Ag + (size_t)row * K + k0 + kc * 8, a_s + c * 8);
        }
        #pragma unroll
        for (int p = 0; p < BN * 8 / 256; p++) {
            int c = p * 256 + tid;
            int row = c >> 3;
            int kc = (c & 7) ^ (row & 7);
            gl_lds16(Wg + (size_t)row * K + k0 + kc * 8, b_s + c * 8);
        }
        __syncthreads();
        #pragma unroll
        for (int s = 0; s < 2; s++) {
            shortx8 af[MI], bf[NI];
            int kc = s * 4 + lkc;
            #pragma unroll
            for (int i = 0; i < MI; i++) {
                int row = wm * (BM / 2) + i * 16 + lr;
                af[i] = *(const shortx8*)(a_s + (row * 8 + (kc ^ (row & 7))) * 8);
            }
            #pragma unroll
            for (int j = 0; j < NI; j++) {
                int row = wn * (BN / 2) + j * 16 + lr;
                bf[j] = *(const shortx8*)(b_s + (row * 8 + (kc ^ (row & 7))) * 8);
            }
            #pragma unroll
            for (int i = 0; i < MI; i++)
                #pragma unroll
                for (int j = 0; j < NI; j++)
                    acc[i][j] = __builtin_amdgcn_mfma_f32_16x16x32_bf16(
                        af[i], bf[j], acc[i][j], 0, 0, 0);
        }
        __syncthreads();
    }

    // epilogue: C/D layout col = lane&15, row = (lane>>4)*4 + r
    int col_l = lane & 15;
    int row_base = (lane >> 4) * 4;
    #pragma unroll
    for (int ni = 0; ni < NI; ni++) {
        int col = n_blk + wn * (BN / 2) + ni * 16 + col_l;
        float bv = bias[col];
        #pragma unroll
        for (int mi = 0; mi < MI; mi++) {
            #pragma unroll
            for (int r = 0; r < 4; r++) {
                int row = m_blk + wm * (BM / 2) + mi * 16 + row_base + r;
                size_t off = (size_t)row * Nn + col;
                float v = acc[mi][ni][r] + bv;
                if (EPI == 1 || EPI == 3) {
                    outF[off] = v + resid[off];
                } else if (EPI == 2) {
                    v = 0.5f * v * (1.0f + erff(v * 0.70710678118f));
                    outB[off] = f2b(v);
                } else {
                    outB[off] = f2b(v);
                }
            }
        }
    }
}

// ---------- windowed attention, MFMA flash-style (unchanged from R3) ----------
__global__ __launch_bounds__(256) void attn_kernel(const u16* __restrict__ qkv,
                                                   const float* __restrict__ rel_bias,
                                                   u16* __restrict__ out) {
    __shared__ u16 k_s[128][72];
    __shared__ u16 v_t[64][152];
    __shared__ u16 p_s[4][16][104];
    __shared__ float s_bias[64];

    int bx = blockIdx.x;
    int n = bx >> 8;
    int h = (bx >> 5) & 7;
    int t0 = (bx & 31) << 6;
    int tid = threadIdx.x, wid = tid >> 6, lane = tid & 63;
    int col = lane & 15, rq = lane >> 4;

    const u16* qrow = qkv + (size_t)(n * 2048 + t0 + wid * 16 + col) * 1536 + h * 64 + rq * 8;
    shortx8 qf0 = *(const shortx8*)qrow;
    shortx8 qf1 = *(const shortx8*)(qrow + 32);

    if (tid < 63) s_bias[tid] = rel_bias[h * 63 + tid];
    if (tid == 63) s_bias[63] = 0.f;

    const uint* qkv_u = (const uint*)qkv;
    for (int idx = tid; idx < 128 * 32; idx += 256) {
        int row = idx >> 5, j = idx & 31;
        int pos = t0 - 31 + row;
        uint kv = 0;
        if (pos >= 0 && pos < 2048)
            kv = qkv_u[(size_t)(n * 2048 + pos) * 768 + 256 + h * 32 + j];
        *(uint*)&k_s[row][j * 2] = kv;
    }
    for (int idx = tid; idx < 144 * 32; idx += 256) {
        int row = idx >> 5, j = idx & 31;
        int pos = t0 - 31 + row;
        uint vv = 0;
        if (pos >= 0 && pos < 2048)
            vv = qkv_u[(size_t)(n * 2048 + pos) * 768 + 512 + h * 32 + j];
        v_t[2 * j][row] = (u16)(vv & 0xffffu);
        v_t[2 * j + 1][row] = (u16)(vv >> 16);
    }
    __syncthreads();

    floatx4 S[5];
    #pragma unroll
    for (int nt = 0; nt < 5; nt++) S[nt] = (floatx4){0.f, 0.f, 0.f, 0.f};
    #pragma unroll
    for (int nt = 0; nt < 5; nt++) {
        const u16* kb = &k_s[wid * 16 + nt * 16 + col][rq * 8];
        shortx8 b0 = *(const shortx8*)kb;
        shortx8 b1 = *(const shortx8*)(kb + 32);
        S[nt] = __builtin_amdgcn_mfma_f32_16x16x32_bf16(qf0, b0, S[nt], 0, 0, 0);
        S[nt] = __builtin_amdgcn_mfma_f32_16x16x32_bf16(qf1, b1, S[nt], 0, 0, 0);
    }

    #pragma unroll
    for (int r = 0; r < 4; r++) {
        int t_row = rq * 4 + r;
        float sc[5];
        float mx = -1e30f;
        #pragma unroll
        for (int nt = 0; nt < 5; nt++) {
            int w = nt * 16 + col - t_row;
            int pos_abs = t0 - 31 + wid * 16 + nt * 16 + col;
            float v;
            if (w < 0 || w > 62) {
                v = -1e30f;
            } else {
                v = S[nt][r] * 0.125f + s_bias[w];
                if (pos_abs < 0 || pos_abs >= 2048) v -= 100.f;
            }
            sc[nt] = v;
            mx = fmaxf(mx, v);
        }
        #pragma unroll
        for (int o = 1; o < 16; o <<= 1) mx = fmaxf(mx, __shfl_xor(mx, o, 64));
        float l = 0.f;
        #pragma unroll
        for (int nt = 0; nt < 5; nt++) {
            sc[nt] = __expf(sc[nt] - mx);
            l += sc[nt];
        }
        #pragma unroll
        for (int o = 1; o < 16; o <<= 1) l += __shfl_xor(l, o, 64);
        float inv = 1.0f / l;
        #pragma unroll
        for (int nt = 0; nt < 5; nt++)
            p_s[wid][t_row][nt * 16 + col] = f2b(sc[nt] * inv);
        p_s[wid][t_row][80 + col] = 0;
    }
    __syncthreads();

    floatx4 O[4];
    #pragma unroll
    for (int dt = 0; dt < 4; dt++) O[dt] = (floatx4){0.f, 0.f, 0.f, 0.f};
    const u16* pr = &p_s[wid][col][rq * 8];
    shortx8 a0 = *(const shortx8*)pr;
    shortx8 a1 = *(const shortx8*)(pr + 32);
    shortx8 a2 = *(const shortx8*)(pr + 64);
    #pragma unroll
    for (int dt = 0; dt < 4; dt++) {
        const u16* vb = &v_t[dt * 16 + col][wid * 16 + rq * 8];
        shortx8 b0 = *(const shortx8*)vb;
        shortx8 b1 = *(const shortx8*)(vb + 32);
        shortx8 b2 = *(const shortx8*)(vb + 64);
        O[dt] = __builtin_amdgcn_mfma_f32_16x16x32_bf16(a0, b0, O[dt], 0, 0, 0);
        O[dt] = __builtin_amdgcn_mfma_f32_16x16x32_bf16(a1, b1, O[dt], 0, 0, 0);
        O[dt] = __builtin_amdgcn_mfma_f32_16x16x32_bf16(a2, b2, O[dt], 0, 0, 0);
    }

    #pragma unroll
    for (int dt = 0; dt < 4; dt++) {
        #pragma unroll
        for (int r = 0; r < 4; r++) {
            int t_row = rq * 4 + r;
            out[(size_t)(n * 2048 + t0 + wid * 16 + t_row) * 512 + h * 64 + dt * 16 + col] =
                f2b(O[dt][r]);
        }
    }
}

// ---------- launcher ----------
extern "C" void kernel_launch(void* const* d_in, const int* in_sizes, int n_in,
                              void* d_out, int out_size, void* d_ws, size_t ws_size,
                              hipStream_t stream) {
    const float* x     = (const float*)d_in[0];
    const float* n1w   = (const float*)d_in[1];
    const float* n1b   = (const float*)d_in[2];
    const float* qkvw  = (const float*)d_in[3];
    const float* qkvbv = (const float*)d_in[4];
    const float* relb  = (const float*)d_in[5];
    const float* projw = (const float*)d_in[6];
    const float* projb = (const float*)d_in[7];
    const float* n2w   = (const float*)d_in[8];
    const float* n2b   = (const float*)d_in[9];
    const float* fc1w  = (const float*)d_in[10];
    const float* fc1b  = (const float*)d_in[11];
    const float* fc2w  = (const float*)d_in[12];
    const float* fc2b  = (const float*)d_in[13];
    float* out = (float*)d_out;

    char* p = (char*)d_ws;
    u16* wq   = (u16*)p;  p += (size_t)786432 * 2;   // qkv_w bf16 (1536x512)
    u16* wp   = (u16*)p;  p += (size_t)262144 * 2;   // proj_w bf16 (512x512)
    u16* w1   = (u16*)p;  p += (size_t)1048576 * 2;  // fc1_w bf16 (2048x512)
    u16* w2   = (u16*)p;  p += (size_t)1048576 * 2;  // fc2_w bf16 (512x2048)
    u16* hb   = (u16*)p;  p += (size_t)2097152 * 2;  // h / h2 bf16 (4096x512)
    u16* qkvb = (u16*)p;  p += (size_t)6291456 * 2;  // qkv bf16 (4096x1536)
    u16* attb = (u16*)p;  p += (size_t)2097152 * 2;  // attn out bf16 (4096x512)
    float* x2 = (float*)p; p += (size_t)2097152 * 4; // x + proj(attn) fp32 (4096x512)
    u16* mb   = (u16*)p;  p += (size_t)8388608 * 2;  // gelu(fc1) bf16 (4096x2048)

    cvt_kernel<<<768, 256, 0, stream>>>(qkvw, wq, 786432 / 4);
    cvt_kernel<<<256, 256, 0, stream>>>(projw, wp, 262144 / 4);
    cvt_kernel<<<1024, 256, 0, stream>>>(fc1w, w1, 1048576 / 4);
    cvt_kernel<<<1024, 256, 0, stream>>>(fc2w, w2, 1048576 / 4);

    ln_kernel<<<4096, 256, 0, stream>>>(x, n1w, n1b, hb);
    // qkv: 4096x1536, K=512 -> 384 blocks
    gemm_lds<128, 128, 0><<<dim3(12, 32), 256, 0, stream>>>(
        hb, wq, qkvbv, nullptr, nullptr, qkvb, 4096, 1536, 512);
    attn_kernel<<<512, 256, 0, stream>>>(qkvb, relb, attb);
    // proj: 4096x512, K=512 -> 128x64 tiles, 256 blocks
    gemm_lds<128, 64, 1><<<dim3(8, 32), 256, 0, stream>>>(
        attb, wp, projb, x, x2, nullptr, 4096, 512, 512);
    ln_kernel<<<4096, 256, 0, stream>>>(x2, n2w, n2b, hb);
    // fc1: 4096x2048, K=512 -> 512 blocks
    gemm_lds<128, 128, 2><<<dim3(16, 32), 256, 0, stream>>>(
        hb, w1, fc1b, nullptr, nullptr, mb, 4096, 2048, 512);
    // fc2: 4096x512, K=2048 -> 128x64 tiles, 256 blocks
    gemm_lds<128, 64, 3><<<dim3(8, 32), 256, 0, stream>>>(
        mb, w2, fc2b, x2, out, nullptr, 4096, 512, 2048);
}

// Round 5
// 195.329 us; speedup vs baseline: 1.9559x; 1.0545x over previous
//
#include <hip/hip_runtime.h>

typedef unsigned short u16;
typedef unsigned int uint;
typedef __attribute__((ext_vector_type(4))) float floatx4;
typedef __attribute__((ext_vector_type(16))) float floatx16;
typedef __attribute__((ext_vector_type(8))) short shortx8;

// ---------- helpers ----------
__device__ __forceinline__ u16 f2b(float f) {
    unsigned int u = __float_as_uint(f);
    unsigned int r = (u + 0x7fffu + ((u >> 16) & 1u)) >> 16;
    return (u16)r;
}
__device__ __forceinline__ float b2f(u16 u) {
    return __uint_as_float(((unsigned int)u) << 16);
}
__device__ __forceinline__ void gl_lds16(const u16* g, u16* l) {
    __builtin_amdgcn_global_load_lds(
        (const __attribute__((address_space(1))) void*)g,
        (__attribute__((address_space(3))) void*)l, 16, 0, 0);
}
// tanh-form GELU: 0.5x(1+tanh(.79788(x+.044715x^3))) = x*e/(e+1), e=exp(2y)
__device__ __forceinline__ float gelu_f(float v) {
    float e = __expf(1.59576912f * v * (1.0f + 0.044715f * v * v));
    return v * e / (e + 1.0f);
}

// ---------- LN row helper (C=512), fp32 in -> bf16 out; 256 threads ----------
__device__ __forceinline__ void ln_row(const float* __restrict__ x,
                                       const float* __restrict__ w,
                                       const float* __restrict__ b,
                                       u16* __restrict__ out, int row,
                                       float* red) {
    const float2* xr = (const float2*)(x + (size_t)row * 512);
    float2 v = xr[threadIdx.x];
    float s = v.x + v.y;
    float s2 = v.x * v.x + v.y * v.y;
    #pragma unroll
    for (int o = 32; o > 0; o >>= 1) {
        s += __shfl_down(s, o, 64);
        s2 += __shfl_down(s2, o, 64);
    }
    int wid = threadIdx.x >> 6, lane = threadIdx.x & 63;
    if (lane == 0) { red[wid] = s; red[4 + wid] = s2; }
    __syncthreads();
    s = red[0] + red[1] + red[2] + red[3];
    s2 = red[4] + red[5] + red[6] + red[7];
    float mu = s * (1.0f / 512.0f);
    float var = s2 * (1.0f / 512.0f) - mu * mu;
    float rstd = rsqrtf(var + 1e-5f);
    float2 wv = ((const float2*)w)[threadIdx.x];
    float2 bv = ((const float2*)b)[threadIdx.x];
    float o0 = (v.x - mu) * rstd * wv.x + bv.x;
    float o1 = (v.y - mu) * rstd * wv.y + bv.y;
    unsigned int pack = (unsigned)f2b(o0) | ((unsigned)f2b(o1) << 16);
    ((unsigned int*)(out + (size_t)row * 512))[threadIdx.x] = pack;
}

// ---------- standalone LN (for LN2) ----------
__global__ __launch_bounds__(256) void ln_kernel(const float* __restrict__ x,
                                                 const float* __restrict__ w,
                                                 const float* __restrict__ b,
                                                 u16* __restrict__ out) {
    __shared__ float red[8];
    ln_row(x, w, b, out, blockIdx.x, red);
}

// ---------- fused prep: cvt all 4 weights + LN1, range-dispatched ----------
// blocks [0,768) qkv_w | [768,1024) proj_w | [1024,2048) fc1_w | [2048,3072) fc2_w
// [3072,7168) LN1 rows
__global__ __launch_bounds__(256) void prep_kernel(
    const float* __restrict__ qkvw, u16* __restrict__ wq,
    const float* __restrict__ projw, u16* __restrict__ wp,
    const float* __restrict__ fc1w, u16* __restrict__ w1,
    const float* __restrict__ fc2w, u16* __restrict__ w2,
    const float* __restrict__ x, const float* __restrict__ n1w,
    const float* __restrict__ n1b, u16* __restrict__ hb) {
    __shared__ float red[8];
    int bi = blockIdx.x;
    if (bi < 3072) {
        const float* src;
        u16* dst;
        int i0;
        if (bi < 768)       { src = qkvw; dst = wq; i0 = bi; }
        else if (bi < 1024) { src = projw; dst = wp; i0 = bi - 768; }
        else if (bi < 2048) { src = fc1w; dst = w1; i0 = bi - 1024; }
        else                { src = fc2w; dst = w2; i0 = bi - 2048; }
        int i = i0 * 256 + threadIdx.x;   // exact block counts: no bound check
        float4 v = ((const float4*)src)[i];
        uint2 o;
        o.x = (unsigned)f2b(v.x) | ((unsigned)f2b(v.y) << 16);
        o.y = (unsigned)f2b(v.z) | ((unsigned)f2b(v.w) << 16);
        ((uint2*)dst)[i] = o;
    } else {
        ln_row(x, n1w, n1b, hb, bi - 3072, red);
    }
}

// ---------- bf16 MFMA GEMM, 32x32x16, m97-style LDS staging ----------
// C[M,N] = A[M,K] @ W[N,K]^T + bias (+epilogue). BK=64, 2x2 waves, wave tile
// (BM/2)x(BN/2) of 32x32 MFMA tiles. LDS: 16B chunks, chunk(row,kc) at
// row*8 + (kc ^ (row&7)) -> staging coalesced, frag ds_read_b128 optimal.
// EPI: 0 bias->bf16 | 1 bias+resid->fp32 | 2 bias+GELU->bf16 | 3 bias+resid->fp32
template <int BM, int BN, int EPI>
__global__ __launch_bounds__(256) void gemm_lds(const u16* __restrict__ A,
                                                const u16* __restrict__ W,
                                                const float* __restrict__ bias,
                                                const float* __restrict__ resid,
                                                float* __restrict__ outF,
                                                u16* __restrict__ outB,
                                                int M, int Nn, int K) {
    constexpr int MI = BM / 2 / 32;      // 32-row A-frags per wave
    constexpr int NI = BN / 2 / 32;      // 32-col B-frags per wave
    __shared__ u16 a_s[BM * 64];
    __shared__ u16 b_s[BN * 64];

    int tid = threadIdx.x;
    int wid = tid >> 6, lane = tid & 63;
    int wm = wid >> 1, wn = wid & 1;
    int m_blk = blockIdx.y * BM;
    int n_blk = blockIdx.x * BN;
    int lr = lane & 31;
    int lk = lane >> 5;                  // k-chunk parity within 16-k sub-tile

    floatx16 acc[MI][NI];
    #pragma unroll
    for (int i = 0; i < MI; i++)
        #pragma unroll
        for (int j = 0; j < NI; j++)
            #pragma unroll
            for (int r = 0; r < 16; r++) acc[i][j][r] = 0.f;

    const u16* Ag = A + (size_t)m_blk * K;
    const u16* Wg = W + (size_t)n_blk * K;

    for (int k0 = 0; k0 < K; k0 += 64) {
        #pragma unroll
        for (int p = 0; p < BM * 8 / 256; p++) {
            int c = p * 256 + tid;
            int row = c >> 3;
            int kc = (c & 7) ^ (row & 7);
            gl_lds16(Ag + (size_t)row * K + k0 + kc * 8, a_s + c * 8);
        }
        #pragma unroll
        for (int p = 0; p < BN * 8 / 256; p++) {
            int c = p * 256 + tid;
            int row = c >> 3;
            int kc = (c & 7) ^ (row & 7);
            gl_lds16(Wg + (size_t)row * K + k0 + kc * 8, b_s + c * 8);
        }
        __syncthreads();
        #pragma unroll
        for (int s = 0; s < 4; s++) {    // 4 sub-tiles of K=16
            shortx8 af[MI], bf[NI];
            int kc = s * 2 + lk;
            #pragma unroll
            for (int i = 0; i < MI; i++) {
                int row = wm * (BM / 2) + i * 32 + lr;
                af[i] = *(const shortx8*)(a_s + (row * 8 + (kc ^ (row & 7))) * 8);
            }
            #pragma unroll
            for (int j = 0; j < NI; j++) {
                int row = wn * (BN / 2) + j * 32 + lr;
                bf[j] = *(const shortx8*)(b_s + (row * 8 + (kc ^ (row & 7))) * 8);
            }
            #pragma unroll
            for (int i = 0; i < MI; i++)
                #pragma unroll
                for (int j = 0; j < NI; j++)
                    acc[i][j] = __builtin_amdgcn_mfma_f32_32x32x16_bf16(
                        af[i], bf[j], acc[i][j], 0, 0, 0);
        }
        __syncthreads();
    }

    // epilogue: C/D layout col = lane&31, row = (reg&3) + 8*(reg>>2) + 4*(lane>>5)
    int col_l = lane & 31;
    int row_q = 4 * (lane >> 5);
    #pragma unroll
    for (int nj = 0; nj < NI; nj++) {
        int col = n_blk + wn * (BN / 2) + nj * 32 + col_l;
        float bv = bias[col];
        #pragma unroll
        for (int mi = 0; mi < MI; mi++) {
            #pragma unroll
            for (int r = 0; r < 16; r++) {
                int row = m_blk + wm * (BM / 2) + mi * 32 + (r & 3) + 8 * (r >> 2) + row_q;
                size_t off = (size_t)row * Nn + col;
                float v = acc[mi][nj][r] + bv;
                if (EPI == 1 || EPI == 3) {
                    outF[off] = v + resid[off];
                } else if (EPI == 2) {
                    outB[off] = f2b(gelu_f(v));
                } else {
                    outB[off] = f2b(v);
                }
            }
        }
    }
}

// ---------- windowed attention, MFMA flash-style ----------
__global__ __launch_bounds__(256) void attn_kernel(const u16* __restrict__ qkv,
                                                   const float* __restrict__ rel_bias,
                                                   u16* __restrict__ out) {
    __shared__ u16 k_s[128][72];
    __shared__ u16 v_t[64][152];
    __shared__ u16 p_s[4][16][104];
    __shared__ float s_bias[64];

    int bx = blockIdx.x;
    int n = bx >> 8;
    int h = (bx >> 5) & 7;
    int t0 = (bx & 31) << 6;
    int tid = threadIdx.x, wid = tid >> 6, lane = tid & 63;
    int col = lane & 15, rq = lane >> 4;

    const u16* qrow = qkv + (size_t)(n * 2048 + t0 + wid * 16 + col) * 1536 + h * 64 + rq * 8;
    shortx8 qf0 = *(const shortx8*)qrow;
    shortx8 qf1 = *(const shortx8*)(qrow + 32);

    if (tid < 63) s_bias[tid] = rel_bias[h * 63 + tid];
    if (tid == 63) s_bias[63] = 0.f;

    const uint* qkv_u = (const uint*)qkv;
    for (int idx = tid; idx < 128 * 32; idx += 256) {
        int row = idx >> 5, j = idx & 31;
        int pos = t0 - 31 + row;
        uint kv = 0;
        if (pos >= 0 && pos < 2048)
            kv = qkv_u[(size_t)(n * 2048 + pos) * 768 + 256 + h * 32 + j];
        *(uint*)&k_s[row][j * 2] = kv;
    }
    for (int idx = tid; idx < 144 * 32; idx += 256) {
        int row = idx >> 5, j = idx & 31;
        int pos = t0 - 31 + row;
        uint vv = 0;
        if (pos >= 0 && pos < 2048)
            vv = qkv_u[(size_t)(n * 2048 + pos) * 768 + 512 + h * 32 + j];
        v_t[2 * j][row] = (u16)(vv & 0xffffu);
        v_t[2 * j + 1][row] = (u16)(vv >> 16);
    }
    __syncthreads();

    floatx4 S[5];
    #pragma unroll
    for (int nt = 0; nt < 5; nt++) S[nt] = (floatx4){0.f, 0.f, 0.f, 0.f};
    #pragma unroll
    for (int nt = 0; nt < 5; nt++) {
        const u16* kb = &k_s[wid * 16 + nt * 16 + col][rq * 8];
        shortx8 b0 = *(const shortx8*)kb;
        shortx8 b1 = *(const shortx8*)(kb + 32);
        S[nt] = __builtin_amdgcn_mfma_f32_16x16x32_bf16(qf0, b0, S[nt], 0, 0, 0);
        S[nt] = __builtin_amdgcn_mfma_f32_16x16x32_bf16(qf1, b1, S[nt], 0, 0, 0);
    }

    #pragma unroll
    for (int r = 0; r < 4; r++) {
        int t_row = rq * 4 + r;
        float sc[5];
        float mx = -1e30f;
        #pragma unroll
        for (int nt = 0; nt < 5; nt++) {
            int w = nt * 16 + col - t_row;
            int pos_abs = t0 - 31 + wid * 16 + nt * 16 + col;
            float v;
            if (w < 0 || w > 62) {
                v = -1e30f;
            } else {
                v = S[nt][r] * 0.125f + s_bias[w];
                if (pos_abs < 0 || pos_abs >= 2048) v -= 100.f;
            }
            sc[nt] = v;
            mx = fmaxf(mx, v);
        }
        #pragma unroll
        for (int o = 1; o < 16; o <<= 1) mx = fmaxf(mx, __shfl_xor(mx, o, 64));
        float l = 0.f;
        #pragma unroll
        for (int nt = 0; nt < 5; nt++) {
            sc[nt] = __expf(sc[nt] - mx);
            l += sc[nt];
        }
        #pragma unroll
        for (int o = 1; o < 16; o <<= 1) l += __shfl_xor(l, o, 64);
        float inv = 1.0f / l;
        #pragma unroll
        for (int nt = 0; nt < 5; nt++)
            p_s[wid][t_row][nt * 16 + col] = f2b(sc[nt] * inv);
        p_s[wid][t_row][80 + col] = 0;
    }
    __syncthreads();

    floatx4 O[4];
    #pragma unroll
    for (int dt = 0; dt < 4; dt++) O[dt] = (floatx4){0.f, 0.f, 0.f, 0.f};
    const u16* pr = &p_s[wid][col][rq * 8];
    shortx8 a0 = *(const shortx8*)pr;
    shortx8 a1 = *(const shortx8*)(pr + 32);
    shortx8 a2 = *(const shortx8*)(pr + 64);
    #pragma unroll
    for (int dt = 0; dt < 4; dt++) {
        const u16* vb = &v_t[dt * 16 + col][wid * 16 + rq * 8];
        shortx8 b0 = *(const shortx8*)vb;
        shortx8 b1 = *(const shortx8*)(vb + 32);
        shortx8 b2 = *(const shortx8*)(vb + 64);
        O[dt] = __builtin_amdgcn_mfma_f32_16x16x32_bf16(a0, b0, O[dt], 0, 0, 0);
        O[dt] = __builtin_amdgcn_mfma_f32_16x16x32_bf16(a1, b1, O[dt], 0, 0, 0);
        O[dt] = __builtin_amdgcn_mfma_f32_16x16x32_bf16(a2, b2, O[dt], 0, 0, 0);
    }

    #pragma unroll
    for (int dt = 0; dt < 4; dt++) {
        #pragma unroll
        for (int r = 0; r < 4; r++) {
            int t_row = rq * 4 + r;
            out[(size_t)(n * 2048 + t0 + wid * 16 + t_row) * 512 + h * 64 + dt * 16 + col] =
                f2b(O[dt][r]);
        }
    }
}

// ---------- launcher ----------
extern "C" void kernel_launch(void* const* d_in, const int* in_sizes, int n_in,
                              void* d_out, int out_size, void* d_ws, size_t ws_size,
                              hipStream_t stream) {
    const float* x     = (const float*)d_in[0];
    const float* n1w   = (const float*)d_in[1];
    const float* n1b   = (const float*)d_in[2];
    const float* qkvw  = (const float*)d_in[3];
    const float* qkvbv = (const float*)d_in[4];
    const float* relb  = (const float*)d_in[5];
    const float* projw = (const float*)d_in[6];
    const float* projb = (const float*)d_in[7];
    const float* n2w   = (const float*)d_in[8];
    const float* n2b   = (const float*)d_in[9];
    const float* fc1w  = (const float*)d_in[10];
    const float* fc1b  = (const float*)d_in[11];
    const float* fc2w  = (const float*)d_in[12];
    const float* fc2b  = (const float*)d_in[13];
    float* out = (float*)d_out;

    char* p = (char*)d_ws;
    u16* wq   = (u16*)p;  p += (size_t)786432 * 2;   // qkv_w bf16 (1536x512)
    u16* wp   = (u16*)p;  p += (size_t)262144 * 2;   // proj_w bf16 (512x512)
    u16* w1   = (u16*)p;  p += (size_t)1048576 * 2;  // fc1_w bf16 (2048x512)
    u16* w2   = (u16*)p;  p += (size_t)1048576 * 2;  // fc2_w bf16 (512x2048)
    u16* hb   = (u16*)p;  p += (size_t)2097152 * 2;  // h / h2 bf16 (4096x512)
    u16* qkvb = (u16*)p;  p += (size_t)6291456 * 2;  // qkv bf16 (4096x1536)
    u16* attb = (u16*)p;  p += (size_t)2097152 * 2;  // attn out bf16 (4096x512)
    float* x2 = (float*)p; p += (size_t)2097152 * 4; // x + proj(attn) fp32 (4096x512)
    u16* mb   = (u16*)p;  p += (size_t)8388608 * 2;  // gelu(fc1) bf16 (4096x2048)

    // prep: all weight cvts + LN1 in one launch
    prep_kernel<<<7168, 256, 0, stream>>>(qkvw, wq, projw, wp, fc1w, w1, fc2w, w2,
                                          x, n1w, n1b, hb);
    // qkv: 4096x1536, K=512
    gemm_lds<128, 128, 0><<<dim3(12, 32), 256, 0, stream>>>(
        hb, wq, qkvbv, nullptr, nullptr, qkvb, 4096, 1536, 512);
    attn_kernel<<<512, 256, 0, stream>>>(qkvb, relb, attb);
    // proj: 4096x512, K=512 -> 256 blocks
    gemm_lds<128, 64, 1><<<dim3(8, 32), 256, 0, stream>>>(
        attb, wp, projb, x, x2, nullptr, 4096, 512, 512);
    ln_kernel<<<4096, 256, 0, stream>>>(x2, n2w, n2b, hb);
    // fc1: 4096x2048, K=512
    gemm_lds<128, 128, 2><<<dim3(16, 32), 256, 0, stream>>>(
        hb, w1, fc1b, nullptr, nullptr, mb, 4096, 2048, 512);
    // fc2: 4096x512, K=2048 -> 256 blocks
    gemm_lds<128, 64, 3><<<dim3(8, 32), 256, 0, stream>>>(
        mb, w2, fc2b, x2, out, nullptr, 4096, 512, 2048);
}

// Round 6
// 178.870 us; speedup vs baseline: 2.1359x; 1.0920x over previous
//
#include <hip/hip_runtime.h>

typedef unsigned short u16;
typedef unsigned int uint;
typedef __attribute__((ext_vector_type(4))) float floatx4;
typedef __attribute__((ext_vector_type(16))) float floatx16;
typedef __attribute__((ext_vector_type(8))) short shortx8;

// ---------- helpers ----------
__device__ __forceinline__ u16 f2b(float f) {
    unsigned int u = __float_as_uint(f);
    unsigned int r = (u + 0x7fffu + ((u >> 16) & 1u)) >> 16;
    return (u16)r;
}
__device__ __forceinline__ float b2f(u16 u) {
    return __uint_as_float(((unsigned int)u) << 16);
}
__device__ __forceinline__ void gl_lds16(const u16* g, u16* l) {
    __builtin_amdgcn_global_load_lds(
        (const __attribute__((address_space(1))) void*)g,
        (__attribute__((address_space(3))) void*)l, 16, 0, 0);
}
// tanh-form GELU: x*e/(e+1), e=exp(1.5958(x+.044715x^3)*2/2)
__device__ __forceinline__ float gelu_f(float v) {
    float e = __expf(1.59576912f * v * (1.0f + 0.044715f * v * v));
    return v * e / (e + 1.0f);
}

// ---------- LN row (fp32 in) ----------
__device__ __forceinline__ void ln_row(const float* __restrict__ x,
                                       const float* __restrict__ w,
                                       const float* __restrict__ b,
                                       u16* __restrict__ out, int row,
                                       float* red) {
    const float2* xr = (const float2*)(x + (size_t)row * 512);
    float2 v = xr[threadIdx.x];
    float s = v.x + v.y;
    float s2 = v.x * v.x + v.y * v.y;
    #pragma unroll
    for (int o = 32; o > 0; o >>= 1) {
        s += __shfl_down(s, o, 64);
        s2 += __shfl_down(s2, o, 64);
    }
    int wid = threadIdx.x >> 6, lane = threadIdx.x & 63;
    if (lane == 0) { red[wid] = s; red[4 + wid] = s2; }
    __syncthreads();
    s = red[0] + red[1] + red[2] + red[3];
    s2 = red[4] + red[5] + red[6] + red[7];
    float mu = s * (1.0f / 512.0f);
    float var = s2 * (1.0f / 512.0f) - mu * mu;
    float rstd = rsqrtf(var + 1e-5f);
    float2 wv = ((const float2*)w)[threadIdx.x];
    float2 bv = ((const float2*)b)[threadIdx.x];
    float o0 = (v.x - mu) * rstd * wv.x + bv.x;
    float o1 = (v.y - mu) * rstd * wv.y + bv.y;
    unsigned int pack = (unsigned)f2b(o0) | ((unsigned)f2b(o1) << 16);
    ((unsigned int*)(out + (size_t)row * 512))[threadIdx.x] = pack;
}

// ---------- LN2: bf16 input (x2 stream) ----------
__global__ __launch_bounds__(256) void ln_kernel_b(const u16* __restrict__ x,
                                                   const float* __restrict__ w,
                                                   const float* __restrict__ b,
                                                   u16* __restrict__ out) {
    __shared__ float red[8];
    int row = blockIdx.x;
    uint pv = ((const uint*)(x + (size_t)row * 512))[threadIdx.x];
    float vx = b2f((u16)(pv & 0xffffu)), vy = b2f((u16)(pv >> 16));
    float s = vx + vy;
    float s2 = vx * vx + vy * vy;
    #pragma unroll
    for (int o = 32; o > 0; o >>= 1) {
        s += __shfl_down(s, o, 64);
        s2 += __shfl_down(s2, o, 64);
    }
    int wid = threadIdx.x >> 6, lane = threadIdx.x & 63;
    if (lane == 0) { red[wid] = s; red[4 + wid] = s2; }
    __syncthreads();
    s = red[0] + red[1] + red[2] + red[3];
    s2 = red[4] + red[5] + red[6] + red[7];
    float mu = s * (1.0f / 512.0f);
    float var = s2 * (1.0f / 512.0f) - mu * mu;
    float rstd = rsqrtf(var + 1e-5f);
    float2 wv = ((const float2*)w)[threadIdx.x];
    float2 bv = ((const float2*)b)[threadIdx.x];
    float o0 = (vx - mu) * rstd * wv.x + bv.x;
    float o1 = (vy - mu) * rstd * wv.y + bv.y;
    unsigned int pack = (unsigned)f2b(o0) | ((unsigned)f2b(o1) << 16);
    ((unsigned int*)(out + (size_t)row * 512))[threadIdx.x] = pack;
}

// ---------- fused prep: cvt 4 weights + LN1 ----------
__global__ __launch_bounds__(256) void prep_kernel(
    const float* __restrict__ qkvw, u16* __restrict__ wq,
    const float* __restrict__ projw, u16* __restrict__ wp,
    const float* __restrict__ fc1w, u16* __restrict__ w1,
    const float* __restrict__ fc2w, u16* __restrict__ w2,
    const float* __restrict__ x, const float* __restrict__ n1w,
    const float* __restrict__ n1b, u16* __restrict__ hb) {
    __shared__ float red[8];
    int bi = blockIdx.x;
    if (bi < 3072) {
        const float* src;
        u16* dst;
        int i0;
        if (bi < 768)       { src = qkvw; dst = wq; i0 = bi; }
        else if (bi < 1024) { src = projw; dst = wp; i0 = bi - 768; }
        else if (bi < 2048) { src = fc1w; dst = w1; i0 = bi - 1024; }
        else                { src = fc2w; dst = w2; i0 = bi - 2048; }
        int i = i0 * 256 + threadIdx.x;
        float4 v = ((const float4*)src)[i];
        uint2 o;
        o.x = (unsigned)f2b(v.x) | ((unsigned)f2b(v.y) << 16);
        o.y = (unsigned)f2b(v.z) | ((unsigned)f2b(v.w) << 16);
        ((uint2*)dst)[i] = o;
    } else {
        ln_row(x, n1w, n1b, hb, bi - 3072, red);
    }
}

// ---------- bf16 MFMA GEMM, 32x32x16, double-buffered LDS ----------
// C[M,N] = A[M,K] @ W[N,K]^T + bias (+epilogue). BK=64, 2x2 waves.
// Prefetch-after-barrier: one __syncthreads per K-iter; loads for iter k+1 are
// in flight during compute of iter k (pays off at low blocks/CU).
// LDS chunk(row,kc) at row*8 + (kc^(row&7)): staging coalesced, frags optimal.
// EPI: 0 bias->bf16 | 1 bias+residF32->bf16 (x2) | 2 bias+GELU->bf16
//      3 bias+residB16->fp32 (d_out)
template <int BM, int BN, int EPI>
__global__ __launch_bounds__(256, 3) void gemm_lds(const u16* __restrict__ A,
                                                   const u16* __restrict__ W,
                                                   const float* __restrict__ bias,
                                                   const float* __restrict__ residF,
                                                   const u16* __restrict__ residB,
                                                   float* __restrict__ outF,
                                                   u16* __restrict__ outB,
                                                   int M, int Nn, int K) {
    constexpr int MI = BM / 2 / 32;
    constexpr int NI = BN / 2 / 32;
    constexpr int ACH = BM * 8 / 256;
    constexpr int BCH = BN * 8 / 256;
    __shared__ u16 a_s[2][BM * 64];
    __shared__ u16 b_s[2][BN * 64];

    int tid = threadIdx.x;
    int wid = tid >> 6, lane = tid & 63;
    int wm = wid >> 1, wn = wid & 1;
    int m_blk = blockIdx.y * BM;
    int n_blk = blockIdx.x * BN;
    int lr = lane & 31;
    int lk = lane >> 5;

    floatx16 acc[MI][NI];
    #pragma unroll
    for (int i = 0; i < MI; i++)
        #pragma unroll
        for (int j = 0; j < NI; j++)
            #pragma unroll
            for (int r = 0; r < 16; r++) acc[i][j][r] = 0.f;

    const u16* Ag = A + (size_t)m_blk * K;
    const u16* Wg = W + (size_t)n_blk * K;

    // per-thread staging coords (constant across iters)
    int arow[ACH], akc[ACH], brow[BCH], bkc[BCH];
    #pragma unroll
    for (int p = 0; p < ACH; p++) {
        int c = p * 256 + tid;
        arow[p] = c >> 3;
        akc[p] = (c & 7) ^ (arow[p] & 7);
    }
    #pragma unroll
    for (int p = 0; p < BCH; p++) {
        int c = p * 256 + tid;
        brow[p] = c >> 3;
        bkc[p] = (c & 7) ^ (brow[p] & 7);
    }

    auto stage = [&](int k0, int buf) {
        #pragma unroll
        for (int p = 0; p < ACH; p++)
            gl_lds16(Ag + (size_t)arow[p] * K + k0 + akc[p] * 8,
                     a_s[buf] + (p * 256 + tid) * 8);
        #pragma unroll
        for (int p = 0; p < BCH; p++)
            gl_lds16(Wg + (size_t)brow[p] * K + k0 + bkc[p] * 8,
                     b_s[buf] + (p * 256 + tid) * 8);
    };

    stage(0, 0);
    int nit = K >> 6;
    for (int it = 0; it < nit; it++) {
        __syncthreads();                      // buf[it&1] ready; prev compute done
        if (it + 1 < nit) stage((it + 1) << 6, (it + 1) & 1);
        int cb = it & 1;
        #pragma unroll
        for (int s = 0; s < 4; s++) {
            shortx8 af[MI], bf[NI];
            int kc = s * 2 + lk;
            #pragma unroll
            for (int i = 0; i < MI; i++) {
                int row = wm * (BM / 2) + i * 32 + lr;
                af[i] = *(const shortx8*)(a_s[cb] + (row * 8 + (kc ^ (row & 7))) * 8);
            }
            #pragma unroll
            for (int j = 0; j < NI; j++) {
                int row = wn * (BN / 2) + j * 32 + lr;
                bf[j] = *(const shortx8*)(b_s[cb] + (row * 8 + (kc ^ (row & 7))) * 8);
            }
            #pragma unroll
            for (int i = 0; i < MI; i++)
                #pragma unroll
                for (int j = 0; j < NI; j++)
                    acc[i][j] = __builtin_amdgcn_mfma_f32_32x32x16_bf16(
                        af[i], bf[j], acc[i][j], 0, 0, 0);
        }
    }

    // epilogue: C/D col = lane&31, row = (r&3) + 8*(r>>2) + 4*(lane>>5)
    int col_l = lane & 31;
    int row_q = 4 * (lane >> 5);
    #pragma unroll
    for (int nj = 0; nj < NI; nj++) {
        int col = n_blk + wn * (BN / 2) + nj * 32 + col_l;
        float bv = bias[col];
        #pragma unroll
        for (int mi = 0; mi < MI; mi++) {
            #pragma unroll
            for (int r = 0; r < 16; r++) {
                int row = m_blk + wm * (BM / 2) + mi * 32 + (r & 3) + 8 * (r >> 2) + row_q;
                size_t off = (size_t)row * Nn + col;
                float v = acc[mi][nj][r] + bv;
                if (EPI == 1) {
                    outB[off] = f2b(v + residF[off]);
                } else if (EPI == 2) {
                    outB[off] = f2b(gelu_f(v));
                } else if (EPI == 3) {
                    outF[off] = v + b2f(residB[off]);
                } else {
                    outB[off] = f2b(v);
                }
            }
        }
    }
}

// ---------- windowed attention, MFMA flash-style (unchanged) ----------
__global__ __launch_bounds__(256) void attn_kernel(const u16* __restrict__ qkv,
                                                   const float* __restrict__ rel_bias,
                                                   u16* __restrict__ out) {
    __shared__ u16 k_s[128][72];
    __shared__ u16 v_t[64][152];
    __shared__ u16 p_s[4][16][104];
    __shared__ float s_bias[64];

    int bx = blockIdx.x;
    int n = bx >> 8;
    int h = (bx >> 5) & 7;
    int t0 = (bx & 31) << 6;
    int tid = threadIdx.x, wid = tid >> 6, lane = tid & 63;
    int col = lane & 15, rq = lane >> 4;

    const u16* qrow = qkv + (size_t)(n * 2048 + t0 + wid * 16 + col) * 1536 + h * 64 + rq * 8;
    shortx8 qf0 = *(const shortx8*)qrow;
    shortx8 qf1 = *(const shortx8*)(qrow + 32);

    if (tid < 63) s_bias[tid] = rel_bias[h * 63 + tid];
    if (tid == 63) s_bias[63] = 0.f;

    const uint* qkv_u = (const uint*)qkv;
    for (int idx = tid; idx < 128 * 32; idx += 256) {
        int row = idx >> 5, j = idx & 31;
        int pos = t0 - 31 + row;
        uint kv = 0;
        if (pos >= 0 && pos < 2048)
            kv = qkv_u[(size_t)(n * 2048 + pos) * 768 + 256 + h * 32 + j];
        *(uint*)&k_s[row][j * 2] = kv;
    }
    for (int idx = tid; idx < 144 * 32; idx += 256) {
        int row = idx >> 5, j = idx & 31;
        int pos = t0 - 31 + row;
        uint vv = 0;
        if (pos >= 0 && pos < 2048)
            vv = qkv_u[(size_t)(n * 2048 + pos) * 768 + 512 + h * 32 + j];
        v_t[2 * j][row] = (u16)(vv & 0xffffu);
        v_t[2 * j + 1][row] = (u16)(vv >> 16);
    }
    __syncthreads();

    floatx4 S[5];
    #pragma unroll
    for (int nt = 0; nt < 5; nt++) S[nt] = (floatx4){0.f, 0.f, 0.f, 0.f};
    #pragma unroll
    for (int nt = 0; nt < 5; nt++) {
        const u16* kb = &k_s[wid * 16 + nt * 16 + col][rq * 8];
        shortx8 b0 = *(const shortx8*)kb;
        shortx8 b1 = *(const shortx8*)(kb + 32);
        S[nt] = __builtin_amdgcn_mfma_f32_16x16x32_bf16(qf0, b0, S[nt], 0, 0, 0);
        S[nt] = __builtin_amdgcn_mfma_f32_16x16x32_bf16(qf1, b1, S[nt], 0, 0, 0);
    }

    #pragma unroll
    for (int r = 0; r < 4; r++) {
        int t_row = rq * 4 + r;
        float sc[5];
        float mx = -1e30f;
        #pragma unroll
        for (int nt = 0; nt < 5; nt++) {
            int w = nt * 16 + col - t_row;
            int pos_abs = t0 - 31 + wid * 16 + nt * 16 + col;
            float v;
            if (w < 0 || w > 62) {
                v = -1e30f;
            } else {
                v = S[nt][r] * 0.125f + s_bias[w];
                if (pos_abs < 0 || pos_abs >= 2048) v -= 100.f;
            }
            sc[nt] = v;
            mx = fmaxf(mx, v);
        }
        #pragma unroll
        for (int o = 1; o < 16; o <<= 1) mx = fmaxf(mx, __shfl_xor(mx, o, 64));
        float l = 0.f;
        #pragma unroll
        for (int nt = 0; nt < 5; nt++) {
            sc[nt] = __expf(sc[nt] - mx);
            l += sc[nt];
        }
        #pragma unroll
        for (int o = 1; o < 16; o <<= 1) l += __shfl_xor(l, o, 64);
        float inv = 1.0f / l;
        #pragma unroll
        for (int nt = 0; nt < 5; nt++)
            p_s[wid][t_row][nt * 16 + col] = f2b(sc[nt] * inv);
        p_s[wid][t_row][80 + col] = 0;
    }
    __syncthreads();

    floatx4 O[4];
    #pragma unroll
    for (int dt = 0; dt < 4; dt++) O[dt] = (floatx4){0.f, 0.f, 0.f, 0.f};
    const u16* pr = &p_s[wid][col][rq * 8];
    shortx8 a0 = *(const shortx8*)pr;
    shortx8 a1 = *(const shortx8*)(pr + 32);
    shortx8 a2 = *(const shortx8*)(pr + 64);
    #pragma unroll
    for (int dt = 0; dt < 4; dt++) {
        const u16* vb = &v_t[dt * 16 + col][wid * 16 + rq * 8];
        shortx8 b0 = *(const shortx8*)vb;
        shortx8 b1 = *(const shortx8*)(vb + 32);
        shortx8 b2 = *(const shortx8*)(vb + 64);
        O[dt] = __builtin_amdgcn_mfma_f32_16x16x32_bf16(a0, b0, O[dt], 0, 0, 0);
        O[dt] = __builtin_amdgcn_mfma_f32_16x16x32_bf16(a1, b1, O[dt], 0, 0, 0);
        O[dt] = __builtin_amdgcn_mfma_f32_16x16x32_bf16(a2, b2, O[dt], 0, 0, 0);
    }

    #pragma unroll
    for (int dt = 0; dt < 4; dt++) {
        #pragma unroll
        for (int r = 0; r < 4; r++) {
            int t_row = rq * 4 + r;
            out[(size_t)(n * 2048 + t0 + wid * 16 + t_row) * 512 + h * 64 + dt * 16 + col] =
                f2b(O[dt][r]);
        }
    }
}

// ---------- launcher ----------
extern "C" void kernel_launch(void* const* d_in, const int* in_sizes, int n_in,
                              void* d_out, int out_size, void* d_ws, size_t ws_size,
                              hipStream_t stream) {
    const float* x     = (const float*)d_in[0];
    const float* n1w   = (const float*)d_in[1];
    const float* n1b   = (const float*)d_in[2];
    const float* qkvw  = (const float*)d_in[3];
    const float* qkvbv = (const float*)d_in[4];
    const float* relb  = (const float*)d_in[5];
    const float* projw = (const float*)d_in[6];
    const float* projb = (const float*)d_in[7];
    const float* n2w   = (const float*)d_in[8];
    const float* n2b   = (const float*)d_in[9];
    const float* fc1w  = (const float*)d_in[10];
    const float* fc1b  = (const float*)d_in[11];
    const float* fc2w  = (const float*)d_in[12];
    const float* fc2b  = (const float*)d_in[13];
    float* out = (float*)d_out;

    char* p = (char*)d_ws;
    u16* wq   = (u16*)p;  p += (size_t)786432 * 2;   // qkv_w bf16 (1536x512)
    u16* wp   = (u16*)p;  p += (size_t)262144 * 2;   // proj_w bf16 (512x512)
    u16* w1   = (u16*)p;  p += (size_t)1048576 * 2;  // fc1_w bf16 (2048x512)
    u16* w2   = (u16*)p;  p += (size_t)1048576 * 2;  // fc2_w bf16 (512x2048)
    u16* hb   = (u16*)p;  p += (size_t)2097152 * 2;  // h / h2 bf16 (4096x512)
    u16* qkvb = (u16*)p;  p += (size_t)6291456 * 2;  // qkv bf16 (4096x1536)
    u16* attb = (u16*)p;  p += (size_t)2097152 * 2;  // attn out bf16 (4096x512)
    u16* x2b  = (u16*)p;  p += (size_t)2097152 * 2;  // x + proj(attn), bf16
    u16* mb   = (u16*)p;  p += (size_t)8388608 * 2;  // gelu(fc1) bf16 (4096x2048)

    prep_kernel<<<7168, 256, 0, stream>>>(qkvw, wq, projw, wp, fc1w, w1, fc2w, w2,
                                          x, n1w, n1b, hb);
    // qkv: 4096x1536, K=512; 128x64 tiles -> 768 blocks (3/CU)
    gemm_lds<128, 64, 0><<<dim3(24, 32), 256, 0, stream>>>(
        hb, wq, qkvbv, nullptr, nullptr, nullptr, qkvb, 4096, 1536, 512);
    attn_kernel<<<512, 256, 0, stream>>>(qkvb, relb, attb);
    // proj: 4096x512, K=512; 64x64 tiles -> 512 blocks (2/CU); x2 = x + proj (bf16)
    gemm_lds<64, 64, 1><<<dim3(8, 64), 256, 0, stream>>>(
        attb, wp, projb, x, nullptr, nullptr, x2b, 4096, 512, 512);
    ln_kernel_b<<<4096, 256, 0, stream>>>(x2b, n2w, n2b, hb);
    // fc1: 4096x2048, K=512; 128x64 tiles -> 1024 blocks (4/CU)
    gemm_lds<128, 64, 2><<<dim3(32, 32), 256, 0, stream>>>(
        hb, w1, fc1b, nullptr, nullptr, nullptr, mb, 4096, 2048, 512);
    // fc2: 4096x512, K=2048; 64x64 tiles -> 512 blocks (2/CU); out = x2 + fc2 (fp32)
    gemm_lds<64, 64, 3><<<dim3(8, 64), 256, 0, stream>>>(
        mb, w2, fc2b, nullptr, x2b, out, nullptr, 4096, 512, 2048);
}

// Round 7
// 177.791 us; speedup vs baseline: 2.1489x; 1.0061x over previous
//
#include <hip/hip_runtime.h>

typedef unsigned short u16;
typedef unsigned int uint;
typedef __attribute__((ext_vector_type(4))) float floatx4;
typedef __attribute__((ext_vector_type(16))) float floatx16;
typedef __attribute__((ext_vector_type(8))) short shortx8;

// ---------- helpers ----------
__device__ __forceinline__ u16 f2b(float f) {
    unsigned int u = __float_as_uint(f);
    unsigned int r = (u + 0x7fffu + ((u >> 16) & 1u)) >> 16;
    return (u16)r;
}
__device__ __forceinline__ float b2f(u16 u) {
    return __uint_as_float(((unsigned int)u) << 16);
}
__device__ __forceinline__ void gl_lds16(const u16* g, u16* l) {
    __builtin_amdgcn_global_load_lds(
        (const __attribute__((address_space(1))) void*)g,
        (__attribute__((address_space(3))) void*)l, 16, 0, 0);
}
// tanh-form GELU
__device__ __forceinline__ float gelu_f(float v) {
    float e = __expf(1.59576912f * v * (1.0f + 0.044715f * v * v));
    return v * e / (e + 1.0f);
}

// ---------- LN row (fp32 in) ----------
__device__ __forceinline__ void ln_row(const float* __restrict__ x,
                                       const float* __restrict__ w,
                                       const float* __restrict__ b,
                                       u16* __restrict__ out, int row,
                                       float* red) {
    const float2* xr = (const float2*)(x + (size_t)row * 512);
    float2 v = xr[threadIdx.x];
    float s = v.x + v.y;
    float s2 = v.x * v.x + v.y * v.y;
    #pragma unroll
    for (int o = 32; o > 0; o >>= 1) {
        s += __shfl_down(s, o, 64);
        s2 += __shfl_down(s2, o, 64);
    }
    int wid = threadIdx.x >> 6, lane = threadIdx.x & 63;
    if (lane == 0) { red[wid] = s; red[4 + wid] = s2; }
    __syncthreads();
    s = red[0] + red[1] + red[2] + red[3];
    s2 = red[4] + red[5] + red[6] + red[7];
    float mu = s * (1.0f / 512.0f);
    float var = s2 * (1.0f / 512.0f) - mu * mu;
    float rstd = rsqrtf(var + 1e-5f);
    float2 wv = ((const float2*)w)[threadIdx.x];
    float2 bv = ((const float2*)b)[threadIdx.x];
    float o0 = (v.x - mu) * rstd * wv.x + bv.x;
    float o1 = (v.y - mu) * rstd * wv.y + bv.y;
    unsigned int pack = (unsigned)f2b(o0) | ((unsigned)f2b(o1) << 16);
    ((unsigned int*)(out + (size_t)row * 512))[threadIdx.x] = pack;
}

// ---------- LN2: bf16 input ----------
__global__ __launch_bounds__(256) void ln_kernel_b(const u16* __restrict__ x,
                                                   const float* __restrict__ w,
                                                   const float* __restrict__ b,
                                                   u16* __restrict__ out) {
    __shared__ float red[8];
    int row = blockIdx.x;
    uint pv = ((const uint*)(x + (size_t)row * 512))[threadIdx.x];
    float vx = b2f((u16)(pv & 0xffffu)), vy = b2f((u16)(pv >> 16));
    float s = vx + vy;
    float s2 = vx * vx + vy * vy;
    #pragma unroll
    for (int o = 32; o > 0; o >>= 1) {
        s += __shfl_down(s, o, 64);
        s2 += __shfl_down(s2, o, 64);
    }
    int wid = threadIdx.x >> 6, lane = threadIdx.x & 63;
    if (lane == 0) { red[wid] = s; red[4 + wid] = s2; }
    __syncthreads();
    s = red[0] + red[1] + red[2] + red[3];
    s2 = red[4] + red[5] + red[6] + red[7];
    float mu = s * (1.0f / 512.0f);
    float var = s2 * (1.0f / 512.0f) - mu * mu;
    float rstd = rsqrtf(var + 1e-5f);
    float2 wv = ((const float2*)w)[threadIdx.x];
    float2 bv = ((const float2*)b)[threadIdx.x];
    float o0 = (vx - mu) * rstd * wv.x + bv.x;
    float o1 = (vy - mu) * rstd * wv.y + bv.y;
    unsigned int pack = (unsigned)f2b(o0) | ((unsigned)f2b(o1) << 16);
    ((unsigned int*)(out + (size_t)row * 512))[threadIdx.x] = pack;
}

// ---------- fused prep: cvt 4 weights + LN1 ----------
__global__ __launch_bounds__(256) void prep_kernel(
    const float* __restrict__ qkvw, u16* __restrict__ wq,
    const float* __restrict__ projw, u16* __restrict__ wp,
    const float* __restrict__ fc1w, u16* __restrict__ w1,
    const float* __restrict__ fc2w, u16* __restrict__ w2,
    const float* __restrict__ x, const float* __restrict__ n1w,
    const float* __restrict__ n1b, u16* __restrict__ hb) {
    __shared__ float red[8];
    int bi = blockIdx.x;
    if (bi < 3072) {
        const float* src;
        u16* dst;
        int i0;
        if (bi < 768)       { src = qkvw; dst = wq; i0 = bi; }
        else if (bi < 1024) { src = projw; dst = wp; i0 = bi - 768; }
        else if (bi < 2048) { src = fc1w; dst = w1; i0 = bi - 1024; }
        else                { src = fc2w; dst = w2; i0 = bi - 2048; }
        int i = i0 * 256 + threadIdx.x;
        float4 v = ((const float4*)src)[i];
        uint2 o;
        o.x = (unsigned)f2b(v.x) | ((unsigned)f2b(v.y) << 16);
        o.y = (unsigned)f2b(v.z) | ((unsigned)f2b(v.w) << 16);
        ((uint2*)dst)[i] = o;
    } else {
        ln_row(x, n1w, n1b, hb, bi - 3072, red);
    }
}

// ---------- bf16 MFMA GEMM, 32x32x16, double-buffered LDS ----------
// C[M,N] = A[M,K] @ W[N,K]^T + bias (+epilogue). 2x2 waves; wave tile
// (BM/2)x(BN/2). Reads:MFMA ratio = 1.0 at 64x64 wave tile (LDS-BW optimal).
// BK templated: long-K GEMMs use BK=128 to halve barrier drains.
// LDS chunk(row,kc) at row*CPR + (kc^(row&(CPR-1))): staging dest linear
// (global_load_lds constraint), frag reads spread over 8 bank-quads (peak BW).
// EPI: 0 bias->bf16 | 1 bias+residF32->bf16 | 2 bias+GELU->bf16
//      3 bias+residB16->fp32 (d_out)
template <int BM, int BN, int BK, int EPI>
__global__ __launch_bounds__(256, 2) void gemm_lds(const u16* __restrict__ A,
                                                   const u16* __restrict__ W,
                                                   const float* __restrict__ bias,
                                                   const float* __restrict__ residF,
                                                   const u16* __restrict__ residB,
                                                   float* __restrict__ outF,
                                                   u16* __restrict__ outB,
                                                   int M, int Nn, int K) {
    constexpr int MI = BM / 2 / 32;
    constexpr int NI = BN / 2 / 32;
    constexpr int CPR = BK / 8;          // 16B chunks per row
    constexpr int KMSK = CPR - 1;
    constexpr int ACH = BM * CPR / 256;
    constexpr int BCH = BN * CPR / 256;
    __shared__ u16 a_s[2][BM * BK];
    __shared__ u16 b_s[2][BN * BK];

    int tid = threadIdx.x;
    int wid = tid >> 6, lane = tid & 63;
    int wm = wid >> 1, wn = wid & 1;
    int m_blk = blockIdx.y * BM;
    int n_blk = blockIdx.x * BN;
    int lr = lane & 31;
    int lk = lane >> 5;

    floatx16 acc[MI][NI];
    #pragma unroll
    for (int i = 0; i < MI; i++)
        #pragma unroll
        for (int j = 0; j < NI; j++)
            #pragma unroll
            for (int r = 0; r < 16; r++) acc[i][j][r] = 0.f;

    const u16* Ag = A + (size_t)m_blk * K;
    const u16* Wg = W + (size_t)n_blk * K;

    int arow[ACH], akc[ACH], brow[BCH], bkc[BCH];
    #pragma unroll
    for (int p = 0; p < ACH; p++) {
        int c = p * 256 + tid;
        arow[p] = c / CPR;
        akc[p] = (c & KMSK) ^ (arow[p] & KMSK);
    }
    #pragma unroll
    for (int p = 0; p < BCH; p++) {
        int c = p * 256 + tid;
        brow[p] = c / CPR;
        bkc[p] = (c & KMSK) ^ (brow[p] & KMSK);
    }

    auto stage = [&](int k0, int buf) {
        #pragma unroll
        for (int p = 0; p < ACH; p++)
            gl_lds16(Ag + (size_t)arow[p] * K + k0 + akc[p] * 8,
                     a_s[buf] + (p * 256 + tid) * 8);
        #pragma unroll
        for (int p = 0; p < BCH; p++)
            gl_lds16(Wg + (size_t)brow[p] * K + k0 + bkc[p] * 8,
                     b_s[buf] + (p * 256 + tid) * 8);
    };

    stage(0, 0);
    int nit = K / BK;
    for (int it = 0; it < nit; it++) {
        __syncthreads();
        if (it + 1 < nit) stage((it + 1) * BK, (it + 1) & 1);
        int cb = it & 1;
        #pragma unroll
        for (int s = 0; s < BK / 16; s++) {
            shortx8 af[MI], bf[NI];
            int kc = s * 2 + lk;
            #pragma unroll
            for (int i = 0; i < MI; i++) {
                int row = wm * (BM / 2) + i * 32 + lr;
                af[i] = *(const shortx8*)(a_s[cb] + (row * CPR + (kc ^ (row & KMSK))) * 8);
            }
            #pragma unroll
            for (int j = 0; j < NI; j++) {
                int row = wn * (BN / 2) + j * 32 + lr;
                bf[j] = *(const shortx8*)(b_s[cb] + (row * CPR + (kc ^ (row & KMSK))) * 8);
            }
            #pragma unroll
            for (int i = 0; i < MI; i++)
                #pragma unroll
                for (int j = 0; j < NI; j++)
                    acc[i][j] = __builtin_amdgcn_mfma_f32_32x32x16_bf16(
                        af[i], bf[j], acc[i][j], 0, 0, 0);
        }
    }

    int col_l = lane & 31;
    int row_q = 4 * (lane >> 5);
    #pragma unroll
    for (int nj = 0; nj < NI; nj++) {
        int col = n_blk + wn * (BN / 2) + nj * 32 + col_l;
        float bv = bias[col];
        #pragma unroll
        for (int mi = 0; mi < MI; mi++) {
            #pragma unroll
            for (int r = 0; r < 16; r++) {
                int row = m_blk + wm * (BM / 2) + mi * 32 + (r & 3) + 8 * (r >> 2) + row_q;
                size_t off = (size_t)row * Nn + col;
                float v = acc[mi][nj][r] + bv;
                if (EPI == 1) {
                    outB[off] = f2b(v + residF[off]);
                } else if (EPI == 2) {
                    outB[off] = f2b(gelu_f(v));
                } else if (EPI == 3) {
                    outF[off] = v + b2f(residB[off]);
                } else {
                    outB[off] = f2b(v);
                }
            }
        }
    }
}

// ---------- windowed attention, MFMA flash-style ----------
__global__ __launch_bounds__(256) void attn_kernel(const u16* __restrict__ qkv,
                                                   const float* __restrict__ rel_bias,
                                                   u16* __restrict__ out) {
    __shared__ u16 k_s[128][72];
    __shared__ u16 v_t[64][152];
    __shared__ u16 p_s[4][16][104];
    __shared__ float s_bias[64];

    int bx = blockIdx.x;
    int n = bx >> 8;
    int h = (bx >> 5) & 7;
    int t0 = (bx & 31) << 6;
    int tid = threadIdx.x, wid = tid >> 6, lane = tid & 63;
    int col = lane & 15, rq = lane >> 4;

    const u16* qrow = qkv + (size_t)(n * 2048 + t0 + wid * 16 + col) * 1536 + h * 64 + rq * 8;
    shortx8 qf0 = *(const shortx8*)qrow;
    shortx8 qf1 = *(const shortx8*)(qrow + 32);

    if (tid < 63) s_bias[tid] = rel_bias[h * 63 + tid];
    if (tid == 63) s_bias[63] = 0.f;

    const uint* qkv_u = (const uint*)qkv;
    for (int idx = tid; idx < 128 * 32; idx += 256) {
        int row = idx >> 5, j = idx & 31;
        int pos = t0 - 31 + row;
        uint kv = 0;
        if (pos >= 0 && pos < 2048)
            kv = qkv_u[(size_t)(n * 2048 + pos) * 768 + 256 + h * 32 + j];
        *(uint*)&k_s[row][j * 2] = kv;
    }
    for (int idx = tid; idx < 144 * 32; idx += 256) {
        int row = idx >> 5, j = idx & 31;
        int pos = t0 - 31 + row;
        uint vv = 0;
        if (pos >= 0 && pos < 2048)
            vv = qkv_u[(size_t)(n * 2048 + pos) * 768 + 512 + h * 32 + j];
        v_t[2 * j][row] = (u16)(vv & 0xffffu);
        v_t[2 * j + 1][row] = (u16)(vv >> 16);
    }
    __syncthreads();

    floatx4 S[5];
    #pragma unroll
    for (int nt = 0; nt < 5; nt++) S[nt] = (floatx4){0.f, 0.f, 0.f, 0.f};
    #pragma unroll
    for (int nt = 0; nt < 5; nt++) {
        const u16* kb = &k_s[wid * 16 + nt * 16 + col][rq * 8];
        shortx8 b0 = *(const shortx8*)kb;
        shortx8 b1 = *(const shortx8*)(kb + 32);
        S[nt] = __builtin_amdgcn_mfma_f32_16x16x32_bf16(qf0, b0, S[nt], 0, 0, 0);
        S[nt] = __builtin_amdgcn_mfma_f32_16x16x32_bf16(qf1, b1, S[nt], 0, 0, 0);
    }

    #pragma unroll
    for (int r = 0; r < 4; r++) {
        int t_row = rq * 4 + r;
        float sc[5];
        float mx = -1e30f;
        #pragma unroll
        for (int nt = 0; nt < 5; nt++) {
            int w = nt * 16 + col - t_row;
            int pos_abs = t0 - 31 + wid * 16 + nt * 16 + col;
            float v;
            if (w < 0 || w > 62) {
                v = -1e30f;
            } else {
                v = S[nt][r] * 0.125f + s_bias[w];
                if (pos_abs < 0 || pos_abs >= 2048) v -= 100.f;
            }
            sc[nt] = v;
            mx = fmaxf(mx, v);
        }
        #pragma unroll
        for (int o = 1; o < 16; o <<= 1) mx = fmaxf(mx, __shfl_xor(mx, o, 64));
        float l = 0.f;
        #pragma unroll
        for (int nt = 0; nt < 5; nt++) {
            sc[nt] = __expf(sc[nt] - mx);
            l += sc[nt];
        }
        #pragma unroll
        for (int o = 1; o < 16; o <<= 1) l += __shfl_xor(l, o, 64);
        float inv = 1.0f / l;
        #pragma unroll
        for (int nt = 0; nt < 5; nt++)
            p_s[wid][t_row][nt * 16 + col] = f2b(sc[nt] * inv);
        p_s[wid][t_row][80 + col] = 0;
    }
    __syncthreads();

    floatx4 O[4];
    #pragma unroll
    for (int dt = 0; dt < 4; dt++) O[dt] = (floatx4){0.f, 0.f, 0.f, 0.f};
    const u16* pr = &p_s[wid][col][rq * 8];
    shortx8 a0 = *(const shortx8*)pr;
    shortx8 a1 = *(const shortx8*)(pr + 32);
    shortx8 a2 = *(const shortx8*)(pr + 64);
    #pragma unroll
    for (int dt = 0; dt < 4; dt++) {
        const u16* vb = &v_t[dt * 16 + col][wid * 16 + rq * 8];
        shortx8 b0 = *(const shortx8*)vb;
        shortx8 b1 = *(const shortx8*)(vb + 32);
        shortx8 b2 = *(const shortx8*)(vb + 64);
        O[dt] = __builtin_amdgcn_mfma_f32_16x16x32_bf16(a0, b0, O[dt], 0, 0, 0);
        O[dt] = __builtin_amdgcn_mfma_f32_16x16x32_bf16(a1, b1, O[dt], 0, 0, 0);
        O[dt] = __builtin_amdgcn_mfma_f32_16x16x32_bf16(a2, b2, O[dt], 0, 0, 0);
    }

    #pragma unroll
    for (int dt = 0; dt < 4; dt++) {
        #pragma unroll
        for (int r = 0; r < 4; r++) {
            int t_row = rq * 4 + r;
            out[(size_t)(n * 2048 + t0 + wid * 16 + t_row) * 512 + h * 64 + dt * 16 + col] =
                f2b(O[dt][r]);
        }
    }
}

// ---------- launcher ----------
extern "C" void kernel_launch(void* const* d_in, const int* in_sizes, int n_in,
                              void* d_out, int out_size, void* d_ws, size_t ws_size,
                              hipStream_t stream) {
    const float* x     = (const float*)d_in[0];
    const float* n1w   = (const float*)d_in[1];
    const float* n1b   = (const float*)d_in[2];
    const float* qkvw  = (const float*)d_in[3];
    const float* qkvbv = (const float*)d_in[4];
    const float* relb  = (const float*)d_in[5];
    const float* projw = (const float*)d_in[6];
    const float* projb = (const float*)d_in[7];
    const float* n2w   = (const float*)d_in[8];
    const float* n2b   = (const float*)d_in[9];
    const float* fc1w  = (const float*)d_in[10];
    const float* fc1b  = (const float*)d_in[11];
    const float* fc2w  = (const float*)d_in[12];
    const float* fc2b  = (const float*)d_in[13];
    float* out = (float*)d_out;

    char* p = (char*)d_ws;
    u16* wq   = (u16*)p;  p += (size_t)786432 * 2;   // qkv_w bf16 (1536x512)
    u16* wp   = (u16*)p;  p += (size_t)262144 * 2;   // proj_w bf16 (512x512)
    u16* w1   = (u16*)p;  p += (size_t)1048576 * 2;  // fc1_w bf16 (2048x512)
    u16* w2   = (u16*)p;  p += (size_t)1048576 * 2;  // fc2_w bf16 (512x2048)
    u16* hb   = (u16*)p;  p += (size_t)2097152 * 2;  // h / h2 bf16 (4096x512)
    u16* qkvb = (u16*)p;  p += (size_t)6291456 * 2;  // qkv bf16 (4096x1536)
    u16* attb = (u16*)p;  p += (size_t)2097152 * 2;  // attn out bf16 (4096x512)
    u16* x2b  = (u16*)p;  p += (size_t)2097152 * 2;  // x + proj(attn), bf16
    u16* mb   = (u16*)p;  p += (size_t)8388608 * 2;  // gelu(fc1) bf16 (4096x2048)

    prep_kernel<<<7168, 256, 0, stream>>>(qkvw, wq, projw, wp, fc1w, w1, fc2w, w2,
                                          x, n1w, n1b, hb);
    // qkv: 4096x1536, K=512; 128x128 tiles (wave 64x64, ratio 1.0) -> 384 blocks
    gemm_lds<128, 128, 64, 0><<<dim3(12, 32), 256, 0, stream>>>(
        hb, wq, qkvbv, nullptr, nullptr, nullptr, qkvb, 4096, 1536, 512);
    attn_kernel<<<512, 256, 0, stream>>>(qkvb, relb, attb);
    // proj: 4096x512, K=512; 64x64 tiles, BK=128 (4 iters) -> 512 blocks
    gemm_lds<64, 64, 128, 1><<<dim3(8, 64), 256, 0, stream>>>(
        attb, wp, projb, x, nullptr, nullptr, x2b, 4096, 512, 512);
    ln_kernel_b<<<4096, 256, 0, stream>>>(x2b, n2w, n2b, hb);
    // fc1: 4096x2048, K=512; 128x128 tiles -> 512 blocks
    gemm_lds<128, 128, 64, 2><<<dim3(16, 32), 256, 0, stream>>>(
        hb, w1, fc1b, nullptr, nullptr, nullptr, mb, 4096, 2048, 512);
    // fc2: 4096x512, K=2048; 64x64 tiles, BK=128 (16 iters) -> 512 blocks
    gemm_lds<64, 64, 128, 3><<<dim3(8, 64), 256, 0, stream>>>(
        mb, w2, fc2b, nullptr, x2b, out, nullptr, 4096, 512, 2048);
}

// Round 8
// 169.178 us; speedup vs baseline: 2.2583x; 1.0509x over previous
//
#include <hip/hip_runtime.h>

typedef unsigned short u16;
typedef unsigned int uint;
typedef __attribute__((ext_vector_type(4))) float floatx4;
typedef __attribute__((ext_vector_type(16))) float floatx16;
typedef __attribute__((ext_vector_type(8))) short shortx8;

// ---------- helpers ----------
__device__ __forceinline__ u16 f2b(float f) {
    unsigned int u = __float_as_uint(f);
    unsigned int r = (u + 0x7fffu + ((u >> 16) & 1u)) >> 16;
    return (u16)r;
}
__device__ __forceinline__ float b2f(u16 u) {
    return __uint_as_float(((unsigned int)u) << 16);
}
__device__ __forceinline__ void gl_lds16(const u16* g, u16* l) {
    __builtin_amdgcn_global_load_lds(
        (const __attribute__((address_space(1))) void*)g,
        (__attribute__((address_space(3))) void*)l, 16, 0, 0);
}
__device__ __forceinline__ float gelu_f(float v) {
    float e = __expf(1.59576912f * v * (1.0f + 0.044715f * v * v));
    return v * e / (e + 1.0f);
}

// ---------- wave-per-row LN (C=512): 8 elems/lane, shuffle-only ----------
__device__ __forceinline__ void ln_row_wave_f32(const float* __restrict__ x,
                                                const float* __restrict__ w,
                                                const float* __restrict__ b,
                                                u16* __restrict__ out, int row) {
    int lane = threadIdx.x & 63;
    const float4* xr = (const float4*)(x + (size_t)row * 512);
    float4 v0 = xr[lane * 2], v1 = xr[lane * 2 + 1];
    float s = v0.x + v0.y + v0.z + v0.w + v1.x + v1.y + v1.z + v1.w;
    float s2 = v0.x * v0.x + v0.y * v0.y + v0.z * v0.z + v0.w * v0.w +
               v1.x * v1.x + v1.y * v1.y + v1.z * v1.z + v1.w * v1.w;
    #pragma unroll
    for (int o = 32; o > 0; o >>= 1) {
        s += __shfl_xor(s, o, 64);
        s2 += __shfl_xor(s2, o, 64);
    }
    float mu = s * (1.0f / 512.0f);
    float var = s2 * (1.0f / 512.0f) - mu * mu;
    float rstd = rsqrtf(var + 1e-5f);
    const float4* wr = (const float4*)w;
    const float4* br = (const float4*)b;
    float4 w0 = wr[lane * 2], w1 = wr[lane * 2 + 1];
    float4 b0 = br[lane * 2], b1 = br[lane * 2 + 1];
    uint4 o4;
    o4.x = (uint)f2b((v0.x - mu) * rstd * w0.x + b0.x) |
           ((uint)f2b((v0.y - mu) * rstd * w0.y + b0.y) << 16);
    o4.y = (uint)f2b((v0.z - mu) * rstd * w0.z + b0.z) |
           ((uint)f2b((v0.w - mu) * rstd * w0.w + b0.w) << 16);
    o4.z = (uint)f2b((v1.x - mu) * rstd * w1.x + b1.x) |
           ((uint)f2b((v1.y - mu) * rstd * w1.y + b1.y) << 16);
    o4.w = (uint)f2b((v1.z - mu) * rstd * w1.z + b1.z) |
           ((uint)f2b((v1.w - mu) * rstd * w1.w + b1.w) << 16);
    ((uint4*)(out + (size_t)row * 512))[lane] = o4;
}

// ---------- LN2: bf16 input, wave-per-row, 4 rows/block ----------
__global__ __launch_bounds__(256) void ln_kernel_b(const u16* __restrict__ x,
                                                   const float* __restrict__ w,
                                                   const float* __restrict__ b,
                                                   u16* __restrict__ out) {
    int row = blockIdx.x * 4 + (threadIdx.x >> 6);
    int lane = threadIdx.x & 63;
    uint4 p = ((const uint4*)(x + (size_t)row * 512))[lane];
    float v[8];
    v[0] = b2f((u16)(p.x & 0xffffu)); v[1] = b2f((u16)(p.x >> 16));
    v[2] = b2f((u16)(p.y & 0xffffu)); v[3] = b2f((u16)(p.y >> 16));
    v[4] = b2f((u16)(p.z & 0xffffu)); v[5] = b2f((u16)(p.z >> 16));
    v[6] = b2f((u16)(p.w & 0xffffu)); v[7] = b2f((u16)(p.w >> 16));
    float s = 0.f, s2 = 0.f;
    #pragma unroll
    for (int i = 0; i < 8; i++) { s += v[i]; s2 += v[i] * v[i]; }
    #pragma unroll
    for (int o = 32; o > 0; o >>= 1) {
        s += __shfl_xor(s, o, 64);
        s2 += __shfl_xor(s2, o, 64);
    }
    float mu = s * (1.0f / 512.0f);
    float var = s2 * (1.0f / 512.0f) - mu * mu;
    float rstd = rsqrtf(var + 1e-5f);
    const float4* wr = (const float4*)w;
    const float4* br = (const float4*)b;
    float4 w0 = wr[lane * 2], w1 = wr[lane * 2 + 1];
    float4 b0 = br[lane * 2], b1 = br[lane * 2 + 1];
    float o8[8];
    o8[0] = (v[0] - mu) * rstd * w0.x + b0.x;
    o8[1] = (v[1] - mu) * rstd * w0.y + b0.y;
    o8[2] = (v[2] - mu) * rstd * w0.z + b0.z;
    o8[3] = (v[3] - mu) * rstd * w0.w + b0.w;
    o8[4] = (v[4] - mu) * rstd * w1.x + b1.x;
    o8[5] = (v[5] - mu) * rstd * w1.y + b1.y;
    o8[6] = (v[6] - mu) * rstd * w1.z + b1.z;
    o8[7] = (v[7] - mu) * rstd * w1.w + b1.w;
    uint4 o4;
    o4.x = (uint)f2b(o8[0]) | ((uint)f2b(o8[1]) << 16);
    o4.y = (uint)f2b(o8[2]) | ((uint)f2b(o8[3]) << 16);
    o4.z = (uint)f2b(o8[4]) | ((uint)f2b(o8[5]) << 16);
    o4.w = (uint)f2b(o8[6]) | ((uint)f2b(o8[7]) << 16);
    ((uint4*)(out + (size_t)row * 512))[lane] = o4;
}

// ---------- fused prep: cvt 4 weights + LN1 (wave-per-row) ----------
// blocks [0,3072): weight cvt | [3072,4096): LN1, 4 rows per block
__global__ __launch_bounds__(256) void prep_kernel(
    const float* __restrict__ qkvw, u16* __restrict__ wq,
    const float* __restrict__ projw, u16* __restrict__ wp,
    const float* __restrict__ fc1w, u16* __restrict__ w1,
    const float* __restrict__ fc2w, u16* __restrict__ w2,
    const float* __restrict__ x, const float* __restrict__ n1w,
    const float* __restrict__ n1b, u16* __restrict__ hb) {
    int bi = blockIdx.x;
    if (bi < 3072) {
        const float* src;
        u16* dst;
        int i0;
        if (bi < 768)       { src = qkvw; dst = wq; i0 = bi; }
        else if (bi < 1024) { src = projw; dst = wp; i0 = bi - 768; }
        else if (bi < 2048) { src = fc1w; dst = w1; i0 = bi - 1024; }
        else                { src = fc2w; dst = w2; i0 = bi - 2048; }
        int i = i0 * 256 + threadIdx.x;
        float4 v = ((const float4*)src)[i];
        uint2 o;
        o.x = (uint)f2b(v.x) | ((uint)f2b(v.y) << 16);
        o.y = (uint)f2b(v.z) | ((uint)f2b(v.w) << 16);
        ((uint2*)dst)[i] = o;
    } else {
        int row = (bi - 3072) * 4 + (threadIdx.x >> 6);
        ln_row_wave_f32(x, n1w, n1b, hb, row);
    }
}

// ---------- GEMM A: 16x16x32 MFMA, MI=NI=4 (m97 frag reuse), dbuf ----------
// 128x128 block, BK=64, 2x2 waves, wave tile 64x64 as 4x4 16-tiles.
// reads/MFMA = 0.5 (each frag feeds 4 MFMAs). EPI: 0 bias->bf16 | 2 bias+GELU->bf16
template <int EPI>
__global__ __launch_bounds__(256, 2) void gemm16(const u16* __restrict__ A,
                                                 const u16* __restrict__ W,
                                                 const float* __restrict__ bias,
                                                 u16* __restrict__ outB,
                                                 int M, int Nn, int K) {
    constexpr int BM = 128, BN = 128, BK = 64;
    __shared__ u16 a_s[2][BM * BK];
    __shared__ u16 b_s[2][BN * BK];

    int tid = threadIdx.x;
    int wid = tid >> 6, lane = tid & 63;
    int wm = wid >> 1, wn = wid & 1;
    int m_blk = blockIdx.x * BM;          // m fastest: same-XCD blocks share B-strip
    int n_blk = blockIdx.y * BN;
    int lr = lane & 15;
    int lkc = lane >> 4;                  // 0..3

    floatx4 acc[4][4];
    #pragma unroll
    for (int i = 0; i < 4; i++)
        #pragma unroll
        for (int j = 0; j < 4; j++) acc[i][j] = (floatx4){0.f, 0.f, 0.f, 0.f};

    const u16* Ag = A + (size_t)m_blk * K;
    const u16* Wg = W + (size_t)n_blk * K;

    int srow = tid >> 3;                  // staging: 4 chunks/thread, rows of 8 chunks
    int skc = (tid & 7) ^ (srow & 7);

    auto stage = [&](int k0, int buf) {
        #pragma unroll
        for (int p = 0; p < 4; p++)
            gl_lds16(Ag + (size_t)(p * 32 + srow) * K + k0 + skc * 8,
                     a_s[buf] + (p * 256 + tid) * 8);
        #pragma unroll
        for (int p = 0; p < 4; p++)
            gl_lds16(Wg + (size_t)(p * 32 + srow) * K + k0 + skc * 8,
                     b_s[buf] + (p * 256 + tid) * 8);
    };

    stage(0, 0);
    int nit = K >> 6;
    for (int it = 0; it < nit; it++) {
        __syncthreads();
        if (it + 1 < nit) stage((it + 1) << 6, (it + 1) & 1);
        int cb = it & 1;
        #pragma unroll
        for (int s = 0; s < 2; s++) {     // two K=32 sub-tiles
            int kc = s * 4 + lkc;
            shortx8 af[4], bf[4];
            #pragma unroll
            for (int i = 0; i < 4; i++) {
                int row = wm * 64 + i * 16 + lr;
                af[i] = *(const shortx8*)(a_s[cb] + (row * 8 + (kc ^ (row & 7))) * 8);
            }
            #pragma unroll
            for (int j = 0; j < 4; j++) {
                int row = wn * 64 + j * 16 + lr;
                bf[j] = *(const shortx8*)(b_s[cb] + (row * 8 + (kc ^ (row & 7))) * 8);
            }
            #pragma unroll
            for (int i = 0; i < 4; i++)
                #pragma unroll
                for (int j = 0; j < 4; j++)
                    acc[i][j] = __builtin_amdgcn_mfma_f32_16x16x32_bf16(
                        af[i], bf[j], acc[i][j], 0, 0, 0);
        }
    }

    // C/D: col = lane&15, row = (lane>>4)*4 + r
    int col_l = lane & 15;
    int row_base = (lane >> 4) * 4;
    #pragma unroll
    for (int nj = 0; nj < 4; nj++) {
        int col = n_blk + wn * 64 + nj * 16 + col_l;
        float bv = bias[col];
        #pragma unroll
        for (int mi = 0; mi < 4; mi++) {
            #pragma unroll
            for (int r = 0; r < 4; r++) {
                int row = m_blk + wm * 64 + mi * 16 + row_base + r;
                size_t off = (size_t)row * Nn + col;
                float v = acc[mi][nj][r] + bv;
                outB[off] = f2b(EPI == 2 ? gelu_f(v) : v);
            }
        }
    }
}

// ---------- GEMM B: 32x32x16, 64x64 block, BK=128, dbuf (N=512 GEMMs) ----------
// EPI: 1 bias+residF32->bf16 | 3 bias+residB16->fp32 (d_out)
template <int EPI>
__global__ __launch_bounds__(256, 2) void gemm32(const u16* __restrict__ A,
                                                 const u16* __restrict__ W,
                                                 const float* __restrict__ bias,
                                                 const float* __restrict__ residF,
                                                 const u16* __restrict__ residB,
                                                 float* __restrict__ outF,
                                                 u16* __restrict__ outB,
                                                 int M, int Nn, int K) {
    constexpr int BM = 64, BN = 64, BK = 128;
    constexpr int CPR = BK / 8, KMSK = CPR - 1;
    __shared__ u16 a_s[2][BM * BK];
    __shared__ u16 b_s[2][BN * BK];

    int tid = threadIdx.x;
    int wid = tid >> 6, lane = tid & 63;
    int wm = wid >> 1, wn = wid & 1;
    int m_blk = blockIdx.x * BM;
    int n_blk = blockIdx.y * BN;
    int lr = lane & 31;
    int lk = lane >> 5;

    floatx16 acc;
    #pragma unroll
    for (int r = 0; r < 16; r++) acc[r] = 0.f;

    const u16* Ag = A + (size_t)m_blk * K;
    const u16* Wg = W + (size_t)n_blk * K;

    int srow = tid / CPR;                 // 4 rows per 64 threads
    int skc = (tid & KMSK) ^ (srow & KMSK);

    auto stage = [&](int k0, int buf) {
        #pragma unroll
        for (int p = 0; p < 4; p++)
            gl_lds16(Ag + (size_t)(p * 16 + srow) * K + k0 + skc * 8,
                     a_s[buf] + (p * 256 + tid) * 8);
        #pragma unroll
        for (int p = 0; p < 4; p++)
            gl_lds16(Wg + (size_t)(p * 16 + srow) * K + k0 + skc * 8,
                     b_s[buf] + (p * 256 + tid) * 8);
    };

    stage(0, 0);
    int nit = K / BK;
    for (int it = 0; it < nit; it++) {
        __syncthreads();
        if (it + 1 < nit) stage((it + 1) * BK, (it + 1) & 1);
        int cb = it & 1;
        #pragma unroll
        for (int s = 0; s < BK / 16; s++) {
            int kc = s * 2 + lk;
            int arow = wm * 32 + lr;
            int brow = wn * 32 + lr;
            shortx8 af = *(const shortx8*)(a_s[cb] + (arow * CPR + (kc ^ (arow & KMSK))) * 8);
            shortx8 bf = *(const shortx8*)(b_s[cb] + (brow * CPR + (kc ^ (brow & KMSK))) * 8);
            acc = __builtin_amdgcn_mfma_f32_32x32x16_bf16(af, bf, acc, 0, 0, 0);
        }
    }

    int col_l = lane & 31;
    int row_q = 4 * (lane >> 5);
    int col = n_blk + wn * 32 + col_l;
    float bv = bias[col];
    #pragma unroll
    for (int r = 0; r < 16; r++) {
        int row = m_blk + wm * 32 + (r & 3) + 8 * (r >> 2) + row_q;
        size_t off = (size_t)row * Nn + col;
        float v = acc[r] + bv;
        if (EPI == 1) outB[off] = f2b(v + residF[off]);
        else          outF[off] = v + b2f(residB[off]);
    }
}

// ---------- windowed attention, MFMA flash-style (unchanged) ----------
__global__ __launch_bounds__(256) void attn_kernel(const u16* __restrict__ qkv,
                                                   const float* __restrict__ rel_bias,
                                                   u16* __restrict__ out) {
    __shared__ u16 k_s[128][72];
    __shared__ u16 v_t[64][152];
    __shared__ u16 p_s[4][16][104];
    __shared__ float s_bias[64];

    int bx = blockIdx.x;
    int n = bx >> 8;
    int h = (bx >> 5) & 7;
    int t0 = (bx & 31) << 6;
    int tid = threadIdx.x, wid = tid >> 6, lane = tid & 63;
    int col = lane & 15, rq = lane >> 4;

    const u16* qrow = qkv + (size_t)(n * 2048 + t0 + wid * 16 + col) * 1536 + h * 64 + rq * 8;
    shortx8 qf0 = *(const shortx8*)qrow;
    shortx8 qf1 = *(const shortx8*)(qrow + 32);

    if (tid < 63) s_bias[tid] = rel_bias[h * 63 + tid];
    if (tid == 63) s_bias[63] = 0.f;

    const uint* qkv_u = (const uint*)qkv;
    for (int idx = tid; idx < 128 * 32; idx += 256) {
        int row = idx >> 5, j = idx & 31;
        int pos = t0 - 31 + row;
        uint kv = 0;
        if (pos >= 0 && pos < 2048)
            kv = qkv_u[(size_t)(n * 2048 + pos) * 768 + 256 + h * 32 + j];
        *(uint*)&k_s[row][j * 2] = kv;
    }
    for (int idx = tid; idx < 144 * 32; idx += 256) {
        int row = idx >> 5, j = idx & 31;
        int pos = t0 - 31 + row;
        uint vv = 0;
        if (pos >= 0 && pos < 2048)
            vv = qkv_u[(size_t)(n * 2048 + pos) * 768 + 512 + h * 32 + j];
        v_t[2 * j][row] = (u16)(vv & 0xffffu);
        v_t[2 * j + 1][row] = (u16)(vv >> 16);
    }
    __syncthreads();

    floatx4 S[5];
    #pragma unroll
    for (int nt = 0; nt < 5; nt++) S[nt] = (floatx4){0.f, 0.f, 0.f, 0.f};
    #pragma unroll
    for (int nt = 0; nt < 5; nt++) {
        const u16* kb = &k_s[wid * 16 + nt * 16 + col][rq * 8];
        shortx8 b0 = *(const shortx8*)kb;
        shortx8 b1 = *(const shortx8*)(kb + 32);
        S[nt] = __builtin_amdgcn_mfma_f32_16x16x32_bf16(qf0, b0, S[nt], 0, 0, 0);
        S[nt] = __builtin_amdgcn_mfma_f32_16x16x32_bf16(qf1, b1, S[nt], 0, 0, 0);
    }

    #pragma unroll
    for (int r = 0; r < 4; r++) {
        int t_row = rq * 4 + r;
        float sc[5];
        float mx = -1e30f;
        #pragma unroll
        for (int nt = 0; nt < 5; nt++) {
            int w = nt * 16 + col - t_row;
            int pos_abs = t0 - 31 + wid * 16 + nt * 16 + col;
            float v;
            if (w < 0 || w > 62) {
                v = -1e30f;
            } else {
                v = S[nt][r] * 0.125f + s_bias[w];
                if (pos_abs < 0 || pos_abs >= 2048) v -= 100.f;
            }
            sc[nt] = v;
            mx = fmaxf(mx, v);
        }
        #pragma unroll
        for (int o = 1; o < 16; o <<= 1) mx = fmaxf(mx, __shfl_xor(mx, o, 64));
        float l = 0.f;
        #pragma unroll
        for (int nt = 0; nt < 5; nt++) {
            sc[nt] = __expf(sc[nt] - mx);
            l += sc[nt];
        }
        #pragma unroll
        for (int o = 1; o < 16; o <<= 1) l += __shfl_xor(l, o, 64);
        float inv = 1.0f / l;
        #pragma unroll
        for (int nt = 0; nt < 5; nt++)
            p_s[wid][t_row][nt * 16 + col] = f2b(sc[nt] * inv);
        p_s[wid][t_row][80 + col] = 0;
    }
    __syncthreads();

    floatx4 O[4];
    #pragma unroll
    for (int dt = 0; dt < 4; dt++) O[dt] = (floatx4){0.f, 0.f, 0.f, 0.f};
    const u16* pr = &p_s[wid][col][rq * 8];
    shortx8 a0 = *(const shortx8*)pr;
    shortx8 a1 = *(const shortx8*)(pr + 32);
    shortx8 a2 = *(const shortx8*)(pr + 64);
    #pragma unroll
    for (int dt = 0; dt < 4; dt++) {
        const u16* vb = &v_t[dt * 16 + col][wid * 16 + rq * 8];
        shortx8 b0 = *(const shortx8*)vb;
        shortx8 b1 = *(const shortx8*)(vb + 32);
        shortx8 b2 = *(const shortx8*)(vb + 64);
        O[dt] = __builtin_amdgcn_mfma_f32_16x16x32_bf16(a0, b0, O[dt], 0, 0, 0);
        O[dt] = __builtin_amdgcn_mfma_f32_16x16x32_bf16(a1, b1, O[dt], 0, 0, 0);
        O[dt] = __builtin_amdgcn_mfma_f32_16x16x32_bf16(a2, b2, O[dt], 0, 0, 0);
    }

    #pragma unroll
    for (int dt = 0; dt < 4; dt++) {
        #pragma unroll
        for (int r = 0; r < 4; r++) {
            int t_row = rq * 4 + r;
            out[(size_t)(n * 2048 + t0 + wid * 16 + t_row) * 512 + h * 64 + dt * 16 + col] =
                f2b(O[dt][r]);
        }
    }
}

// ---------- launcher ----------
extern "C" void kernel_launch(void* const* d_in, const int* in_sizes, int n_in,
                              void* d_out, int out_size, void* d_ws, size_t ws_size,
                              hipStream_t stream) {
    const float* x     = (const float*)d_in[0];
    const float* n1w   = (const float*)d_in[1];
    const float* n1b   = (const float*)d_in[2];
    const float* qkvw  = (const float*)d_in[3];
    const float* qkvbv = (const float*)d_in[4];
    const float* relb  = (const float*)d_in[5];
    const float* projw = (const float*)d_in[6];
    const float* projb = (const float*)d_in[7];
    const float* n2w   = (const float*)d_in[8];
    const float* n2b   = (const float*)d_in[9];
    const float* fc1w  = (const float*)d_in[10];
    const float* fc1b  = (const float*)d_in[11];
    const float* fc2w  = (const float*)d_in[12];
    const float* fc2b  = (const float*)d_in[13];
    float* out = (float*)d_out;

    char* p = (char*)d_ws;
    u16* wq   = (u16*)p;  p += (size_t)786432 * 2;   // qkv_w bf16 (1536x512)
    u16* wp   = (u16*)p;  p += (size_t)262144 * 2;   // proj_w bf16 (512x512)
    u16* w1   = (u16*)p;  p += (size_t)1048576 * 2;  // fc1_w bf16 (2048x512)
    u16* w2   = (u16*)p;  p += (size_t)1048576 * 2;  // fc2_w bf16 (512x2048)
    u16* hb   = (u16*)p;  p += (size_t)2097152 * 2;  // h / h2 bf16 (4096x512)
    u16* qkvb = (u16*)p;  p += (size_t)6291456 * 2;  // qkv bf16 (4096x1536)
    u16* attb = (u16*)p;  p += (size_t)2097152 * 2;  // attn out bf16 (4096x512)
    u16* x2b  = (u16*)p;  p += (size_t)2097152 * 2;  // x + proj(attn), bf16
    u16* mb   = (u16*)p;  p += (size_t)8388608 * 2;  // gelu(fc1) bf16 (4096x2048)

    prep_kernel<<<4096, 256, 0, stream>>>(qkvw, wq, projw, wp, fc1w, w1, fc2w, w2,
                                          x, n1w, n1b, hb);
    // qkv: 4096x1536, K=512; 16x16 MI=NI=4, grid m-fastest
    gemm16<0><<<dim3(32, 12), 256, 0, stream>>>(hb, wq, qkvbv, qkvb, 4096, 1536, 512);
    attn_kernel<<<512, 256, 0, stream>>>(qkvb, relb, attb);
    // proj: 4096x512, K=512; x2 = x + proj (bf16)
    gemm32<1><<<dim3(64, 8), 256, 0, stream>>>(attb, wp, projb, x, nullptr,
                                               nullptr, x2b, 4096, 512, 512);
    ln_kernel_b<<<1024, 256, 0, stream>>>(x2b, n2w, n2b, hb);
    // fc1: 4096x2048, K=512
    gemm16<2><<<dim3(32, 16), 256, 0, stream>>>(hb, w1, fc1b, mb, 4096, 2048, 512);
    // fc2: 4096x512, K=2048; out = x2 + fc2 (fp32)
    gemm32<3><<<dim3(64, 8), 256, 0, stream>>>(mb, w2, fc2b, nullptr, x2b,
                                               out, nullptr, 4096, 512, 2048);
}